// Round 21
// baseline (434.215 us; speedup 1.0000x reference)
//
#include <hip/hip_runtime.h>
#include <stdint.h>

typedef float f32x4 __attribute__((ext_vector_type(4)));
typedef _Float16 f16x8 __attribute__((ext_vector_type(8)));
typedef unsigned short u16;

#define DEVI static __device__ __forceinline__

DEVI u16 f2h(float f){ _Float16 h = (_Float16)f; return __builtin_bit_cast(u16, h); }
DEVI float h2f(u16 b){ return (float)__builtin_bit_cast(_Float16, b); }
// XOR-swizzled u16 index into a [rows][64] u16 LDS tile (row pitch 128B) — proven 0-conflict (R5).
DEVI int swz(int row, int col){ return (row << 6) + (col ^ ((row & 7) << 3)); }

static constexpr unsigned RANK = 120795954u;   // floor(0.9 * (2*16*2048*2048 - 1))
static constexpr float QFRAC = 0.3f;           // frac part of 0.9*(n-1)
static constexpr float CW = 1.0f / 512.0f;     // coarse bin width over [0,16) (s2 space)
static constexpr unsigned CAP = 1u << 20;      // candidate slots
static constexpr float EPS_REF = 6e-6f;        // boundary band (s2 space)
static constexpr float QSCALE = 0.18033688011112042f;  // 0.125/ln2 folded into stored q

// ---------------- fused split: all 5 inputs -> f16 hi (+ lo where needed) ----------
__global__ __launch_bounds__(256) void split_all(
    const float* __restrict__ x,  const float* __restrict__ wq,
    const float* __restrict__ wk, const float* __restrict__ wv,
    const float* __restrict__ wo,
    u16* __restrict__ xh,  u16* __restrict__ xl,
    u16* __restrict__ wqh, u16* __restrict__ wql,
    u16* __restrict__ wkh, u16* __restrict__ wkl,
    u16* __restrict__ wvh, u16* __restrict__ woh)
{
  const int stride = gridDim.x * 256;
  for (int i = blockIdx.x * 256 + threadIdx.x; i < 2097152; i += stride){
    const float* src; u16* hi; u16* lo; int off;
    if (i < 1048576)      { src = x;  hi = xh;  lo = xl;  off = i; }
    else if (i < 1310720) { src = wq; hi = wqh; lo = wql; off = i - 1048576; }
    else if (i < 1572864) { src = wk; hi = wkh; lo = wkl; off = i - 1310720; }
    else if (i < 1835008) { src = wv; hi = wvh; lo = nullptr; off = i - 1572864; }
    else                  { src = wo; hi = woh; lo = nullptr; off = i - 1835008; }
    float4 v = ((const float4*)src)[off];
    u16 h0 = f2h(v.x), h1 = f2h(v.y), h2 = f2h(v.z), h3 = f2h(v.w);
    ((ushort4*)hi)[off] = make_ushort4(h0, h1, h2, h3);
    if (lo)
      ((ushort4*)lo)[off] = make_ushort4(f2h(v.x - h2f(h0)), f2h(v.y - h2f(h1)),
                                         f2h(v.z - h2f(h2)), f2h(v.w - h2f(h3)));
  }
}

// ---- fused Q+K+V projection GEMM, single launch (48x32 grid, 2-wave packing) ------
// which = blockIdx.x>>4: 0=Q (3-term, *QSCALE, hi/lo), 1=K (3-term, hi/lo),
// 2=V (1-term hi-only, transposed store). Top-level block-uniform branch; each body
// is internally branch-free (R14 lesson: no per-iteration conditionals).
__global__ __launch_bounds__(256) void gemm_projQKV(
    const u16* __restrict__ Ah, const u16* __restrict__ Al,
    const u16* __restrict__ wqh, const u16* __restrict__ wql,
    const u16* __restrict__ wkh, const u16* __restrict__ wkl,
    const u16* __restrict__ wvh,
    u16* __restrict__ qh, u16* __restrict__ ql,
    u16* __restrict__ kh, u16* __restrict__ kl, u16* __restrict__ vth)
{
  __shared__ u16 lAh[128*64], lAl[128*64];
  __shared__ u16 lBh[64*64],  lBl[64*64];
  const int tid = threadIdx.x;
  const int which = blockIdx.x >> 4;
  const int m0 = blockIdx.y * 128, n0 = (blockIdx.x & 15) * 64;
  const int lane = tid & 63, w = tid >> 6;
  const int wm = w >> 1, wn = w & 1;
  const int g = lane >> 4, c = lane & 15;

  if (which == 2){
    // ---------------- V body: 1-term hi-only, transposed store ----------------
    f32x4 acc[4][2];
    #pragma unroll
    for (int i = 0; i < 4; i++)
      #pragma unroll
      for (int j = 0; j < 2; j++) acc[i][j] = f32x4{0,0,0,0};

    for (int k0 = 0; k0 < 1024; k0 += 64){
      __syncthreads();
      #pragma unroll
      for (int i = 0; i < 4; i++){
        int ch = tid + i*256, row = ch >> 3, c8 = ch & 7;
        *(uint4*)&lAh[swz(row, c8*8)] = *(const uint4*)&Ah[(size_t)(m0 + row) * 1024 + k0 + c8*8];
      }
      #pragma unroll
      for (int i = 0; i < 2; i++){
        int ch = tid + i*256, row = ch >> 3, c8 = ch & 7;
        *(uint4*)&lBh[swz(row, c8*8)] = *(const uint4*)&wvh[(size_t)(n0 + row) * 1024 + k0 + c8*8];
      }
      __syncthreads();
      f16x8 ah[4][2], bh[2][2];
      #pragma unroll
      for (int mf = 0; mf < 4; mf++)
        #pragma unroll
        for (int ks = 0; ks < 2; ks++)
          ah[mf][ks] = *(const f16x8*)&lAh[swz(wm*64 + mf*16 + c, ks*32 + g*8)];
      #pragma unroll
      for (int nf = 0; nf < 2; nf++)
        #pragma unroll
        for (int ks = 0; ks < 2; ks++)
          bh[nf][ks] = *(const f16x8*)&lBh[swz(wn*32 + nf*16 + c, ks*32 + g*8)];
      __builtin_amdgcn_s_setprio(1);
      #pragma unroll
      for (int mf = 0; mf < 4; mf++)
        #pragma unroll
        for (int nf = 0; nf < 2; nf++)
          #pragma unroll
          for (int ks = 0; ks < 2; ks++)
            acc[mf][nf] = __builtin_amdgcn_mfma_f32_16x16x32_f16(ah[mf][ks], bh[nf][ks], acc[mf][nf], 0,0,0);
      __builtin_amdgcn_s_setprio(0);
    }
    #pragma unroll
    for (int mf = 0; mf < 4; mf++)
      #pragma unroll
      for (int nf = 0; nf < 2; nf++)
        #pragma unroll
        for (int r = 0; r < 4; r++){
          int m = m0 + wm*64 + mf*16 + g*4 + r;
          int n = n0 + wn*32 + nf*16 + c;
          int b = m >> 11, s = m & 2047, h = n >> 6, d = n & 63;
          size_t idx = (((size_t)(b*16 + h)) * 64 + d) * 2048 + s;
          vth[idx] = f2h(acc[mf][nf][r]);
        }
    return;
  }

  // ---------------- Q/K body: 3-term, branch-free inner loops ----------------
  const u16* __restrict__ Bh = which == 0 ? wqh : wkh;
  const u16* __restrict__ Bl = which == 0 ? wql : wkl;
  f32x4 acc[4][2];
  #pragma unroll
  for (int i = 0; i < 4; i++)
    #pragma unroll
    for (int j = 0; j < 2; j++) acc[i][j] = f32x4{0,0,0,0};

  for (int k0 = 0; k0 < 1024; k0 += 64){
    __syncthreads();
    #pragma unroll
    for (int i = 0; i < 4; i++){                     // A: 128 rows x 64 u16
      int ch = tid + i*256, row = ch >> 3, c8 = ch & 7;
      int di = swz(row, c8*8);
      size_t ga = (size_t)(m0 + row) * 1024 + k0 + c8*8;
      *(uint4*)&lAh[di] = *(const uint4*)&Ah[ga];
      *(uint4*)&lAl[di] = *(const uint4*)&Al[ga];
    }
    #pragma unroll
    for (int i = 0; i < 2; i++){                     // B: 64 rows x 64 u16
      int ch = tid + i*256, row = ch >> 3, c8 = ch & 7;
      int di = swz(row, c8*8);
      size_t gb = (size_t)(n0 + row) * 1024 + k0 + c8*8;
      *(uint4*)&lBh[di] = *(const uint4*)&Bh[gb];
      *(uint4*)&lBl[di] = *(const uint4*)&Bl[gb];
    }
    __syncthreads();
    f16x8 ah[4][2], al[4][2], bh[2][2], bl[2][2];
    #pragma unroll
    for (int mf = 0; mf < 4; mf++)
      #pragma unroll
      for (int ks = 0; ks < 2; ks++){
        int off = swz(wm*64 + mf*16 + c, ks*32 + g*8);
        ah[mf][ks] = *(const f16x8*)&lAh[off];
        al[mf][ks] = *(const f16x8*)&lAl[off];
      }
    #pragma unroll
    for (int nf = 0; nf < 2; nf++)
      #pragma unroll
      for (int ks = 0; ks < 2; ks++){
        int off = swz(wn*32 + nf*16 + c, ks*32 + g*8);
        bh[nf][ks] = *(const f16x8*)&lBh[off];
        bl[nf][ks] = *(const f16x8*)&lBl[off];
      }
    __builtin_amdgcn_s_setprio(1);
    #pragma unroll
    for (int mf = 0; mf < 4; mf++)
      #pragma unroll
      for (int nf = 0; nf < 2; nf++)
        #pragma unroll
        for (int ks = 0; ks < 2; ks++){
          acc[mf][nf] = __builtin_amdgcn_mfma_f32_16x16x32_f16(ah[mf][ks], bh[nf][ks], acc[mf][nf], 0,0,0);
          acc[mf][nf] = __builtin_amdgcn_mfma_f32_16x16x32_f16(ah[mf][ks], bl[nf][ks], acc[mf][nf], 0,0,0);
          acc[mf][nf] = __builtin_amdgcn_mfma_f32_16x16x32_f16(al[mf][ks], bh[nf][ks], acc[mf][nf], 0,0,0);
        }
    __builtin_amdgcn_s_setprio(0);
  }
  #pragma unroll
  for (int mf = 0; mf < 4; mf++)
    #pragma unroll
    for (int nf = 0; nf < 2; nf++)
      #pragma unroll
      for (int r = 0; r < 4; r++){
        int m = m0 + wm*64 + mf*16 + g*4 + r;
        int n = n0 + wn*32 + nf*16 + c;
        float v = acc[mf][nf][r];
        int b = m >> 11, s = m & 2047, h = n >> 6, d = n & 63;
        size_t idx = (((size_t)(b*16 + h)) * 2048 + s) * 64 + d;
        if (which == 0){
          v *= QSCALE;                          // fold 0.125/ln2 into stored q
          u16 hv = f2h(v);
          qh[idx] = hv; ql[idx] = f2h(v - h2f(hv));
        } else {
          u16 hv = f2h(v);
          kh[idx] = hv; kl[idx] = f2h(v - h2f(hv));
        }
      }
}

// ---- output projection GEMM: hi-only 1-term, 64x64 tiles (1024 blocks, 4/CU) ------
__global__ __launch_bounds__(256) void gemm_out(
    const u16* __restrict__ Ahi, const u16* __restrict__ Bhi,
    float* __restrict__ out)
{
  __shared__ u16 lAh[64*64];
  __shared__ u16 lBh[64*64];
  const int tid = threadIdx.x;
  const int m0 = blockIdx.y * 64, n0 = blockIdx.x * 64;
  const int lane = tid & 63, w = tid >> 6;
  const int wm = w >> 1, wn = w & 1;
  const int g = lane >> 4, c = lane & 15;
  f32x4 acc[2][2];
  #pragma unroll
  for (int i = 0; i < 2; i++)
    #pragma unroll
    for (int j = 0; j < 2; j++) acc[i][j] = f32x4{0,0,0,0};

  for (int k0 = 0; k0 < 1024; k0 += 64){
    __syncthreads();
    #pragma unroll
    for (int i = 0; i < 2; i++){
      int ch = tid + i*256, row = ch >> 3, c8 = ch & 7;
      *(uint4*)&lAh[swz(row, c8*8)] = *(const uint4*)&Ahi[(size_t)(m0 + row) * 1024 + k0 + c8*8];
    }
    #pragma unroll
    for (int i = 0; i < 2; i++){
      int ch = tid + i*256, row = ch >> 3, c8 = ch & 7;
      *(uint4*)&lBh[swz(row, c8*8)] = *(const uint4*)&Bhi[(size_t)(n0 + row) * 1024 + k0 + c8*8];
    }
    __syncthreads();
    f16x8 ah[2][2], bh[2][2];
    #pragma unroll
    for (int mf = 0; mf < 2; mf++)
      #pragma unroll
      for (int ks = 0; ks < 2; ks++)
        ah[mf][ks] = *(const f16x8*)&lAh[swz(wm*32 + mf*16 + c, ks*32 + g*8)];
    #pragma unroll
    for (int nf = 0; nf < 2; nf++)
      #pragma unroll
      for (int ks = 0; ks < 2; ks++)
        bh[nf][ks] = *(const f16x8*)&lBh[swz(wn*32 + nf*16 + c, ks*32 + g*8)];
    __builtin_amdgcn_s_setprio(1);
    #pragma unroll
    for (int mf = 0; mf < 2; mf++)
      #pragma unroll
      for (int nf = 0; nf < 2; nf++)
        #pragma unroll
        for (int ks = 0; ks < 2; ks++)
          acc[mf][nf] = __builtin_amdgcn_mfma_f32_16x16x32_f16(ah[mf][ks], bh[nf][ks], acc[mf][nf], 0,0,0);
    __builtin_amdgcn_s_setprio(0);
  }
  #pragma unroll
  for (int mf = 0; mf < 2; mf++)
    #pragma unroll
    for (int nf = 0; nf < 2; nf++)
      #pragma unroll
      for (int r = 0; r < 4; r++){
        int m = m0 + wm*32 + mf*16 + g*4 + r;
        int n = n0 + wn*32 + nf*16 + c;
        out[(size_t)m * 1024 + n] = acc[mf][nf][r];
      }
}

// ------- exact f64 score (s2 space) of stored q*,k — bit-identical everywhere -------
DEVI double exact_score(const u16* __restrict__ qh, const u16* __restrict__ ql,
                        const u16* __restrict__ kh, const u16* __restrict__ kl,
                        size_t base, int q, int k, int lane){
  size_t qo = base + (size_t)q * 64 + lane;
  size_t ko = base + (size_t)k * 64 + lane;
  double qd = (double)h2f(qh[qo]) + (double)h2f(ql[qo]);
  double kd = (double)h2f(kh[ko]) + (double)h2f(kl[ko]);
  double p = qd * kd;
  #pragma unroll
  for (int d = 1; d < 64; d <<= 1) p += __shfl_xor(p, d, 64);
  return p;
}

// ------ pass A: subsampled coarse histogram (f16-hi QK, s2 space), kt-split x4 ------
__global__ __launch_bounds__(256) void hist_sub(const u16* __restrict__ qh,
    const u16* __restrict__ kh, unsigned* __restrict__ ghist){
  __shared__ u16 lK[64*64];
  __shared__ unsigned lh[8192];
  const int tid = threadIdx.x, lane = tid & 63, w = tid >> 6;
  const int g = lane >> 4, c = lane & 15;
  const int bh = blockIdx.x >> 3, rem = blockIdx.x & 7;
  const int qt = rem & 1, quarter = rem >> 1;
  const int qrow0 = qt*64 + w*16;
  const size_t base = (size_t)bh * (2048*64);
  #pragma unroll
  for (int i = 0; i < 32; i++) lh[tid + i*256] = 0u;
  f16x8 qf[2];
  #pragma unroll
  for (int ks = 0; ks < 2; ks++)
    qf[ks] = *(const f16x8*)&qh[base + (size_t)(qrow0 + c)*64 + ks*32 + g*8];

  const int kt0 = quarter * 8;
  for (int kt = kt0; kt < kt0 + 8; kt++){
    __syncthreads();
    #pragma unroll
    for (int i = 0; i < 2; i++){
      int ch = tid + i*256, row = ch >> 3, c8 = ch & 7;
      *(uint4*)&lK[swz(row, c8*8)] = *(const uint4*)&kh[base + (size_t)(kt*64 + row)*64 + c8*8];
    }
    __syncthreads();
    #pragma unroll
    for (int nf = 0; nf < 4; nf++){
      f16x8 k0 = *(const f16x8*)&lK[swz(nf*16 + c, g*8)];
      f16x8 k1 = *(const f16x8*)&lK[swz(nf*16 + c, 32 + g*8)];
      f32x4 a = f32x4{0,0,0,0};
      a = __builtin_amdgcn_mfma_f32_16x16x32_f16(qf[0], k0, a, 0,0,0);
      a = __builtin_amdgcn_mfma_f32_16x16x32_f16(qf[1], k1, a, 0,0,0);
      #pragma unroll
      for (int r = 0; r < 4; r++){
        float v = __builtin_fabsf(a[r]);
        int idx = (int)fminf(v * 512.f, 8191.f);
        atomicAdd(&lh[idx], 1u);
      }
    }
  }
  __syncthreads();
  #pragma unroll
  for (int i = 0; i < 32; i++){
    unsigned cnt = lh[tid + i*256];
    if (cnt) atomicAdd(&ghist[tid + i*256], cnt);
  }
}

// ---------------- window scan (1 block) ----------------
__global__ __launch_bounds__(256) void scan_window(const unsigned* __restrict__ ghist,
    float* __restrict__ sc){
  __shared__ unsigned bins[8192];
  __shared__ unsigned part[256];
  int tid = threadIdx.x;
  unsigned s = 0;
  for (int i = 0; i < 32; i++){ unsigned v = ghist[tid*32 + i]; bins[tid*32 + i] = v; s += v; }
  part[tid] = s;
  __syncthreads();
  if (tid == 0){
    unsigned long long total = 0;
    for (int i = 0; i < 256; i++) total += part[i];
    unsigned long long target = (unsigned long long)(0.9 * (double)total);
    unsigned long long cum = 0; int seg = 0;
    for (; seg < 255; seg++){ if (cum + part[seg] > target) break; cum += part[seg]; }
    int b = seg * 32;
    while (b < 8191 && cum + bins[b] <= target){ cum += bins[b]; b++; }
    int blo = b - 4; if (blo < 0) blo = 0;
    int bhi = b + 5; if (bhi > 8191) bhi = 8191;
    sc[0] = (float)blo * CW;
    sc[1] = (float)bhi * CW;
  }
}

// ---- pass B: LDS-staged K (4-kt per barrier pair), block buffer, rowmax ----------
__global__ __launch_bounds__(256) void collect_k(const u16* __restrict__ qh,
    const u16* __restrict__ kh, const float* __restrict__ sc,
    unsigned* __restrict__ candidx, unsigned* __restrict__ ctr,
    float* __restrict__ rowmax){
  __shared__ u16 lK[4][64*64];                  // 32 KB: four K-tiles per barrier pair
  __shared__ unsigned lbuf[2048];               // 8 KB (mean fill ~460/block; overflow -> global)
  __shared__ unsigned lcnt, gbase;
  const int tid = threadIdx.x, lane = tid & 63, w = tid >> 6;
  const int g = lane >> 4, c = lane & 15;
  const int wid = (blockIdx.x & 7) * 128 + (blockIdx.x >> 3);   // XCD swizzle (1024)
  const int bh = wid >> 5, qt = wid & 31;
  const int qrow0 = qt*64 + w*16;
  const size_t base = (size_t)bh * (2048*64);
  const float lo = sc[0], hi = sc[1];
  if (tid == 0) lcnt = 0u;
  f16x8 qf[2];
  #pragma unroll
  for (int ks = 0; ks < 2; ks++)
    qf[ks] = *(const f16x8*)&qh[base + (size_t)(qrow0 + c)*64 + ks*32 + g*8];
  unsigned cnt = 0;
  float rm[4] = {-1e30f, -1e30f, -1e30f, -1e30f};

  for (int kt4 = 0; kt4 < 8; kt4++){
    __syncthreads();
    #pragma unroll
    for (int t = 0; t < 4; t++)
      #pragma unroll
      for (int i = 0; i < 2; i++){
        int ch = tid + i*256, row = ch >> 3, c8 = ch & 7;
        *(uint4*)&lK[t][swz(row, c8*8)] =
            *(const uint4*)&kh[base + (size_t)((kt4*4 + t)*64 + row)*64 + c8*8];
      }
    __syncthreads();
    #pragma unroll
    for (int t = 0; t < 4; t++){
      const int kt = kt4*4 + t;
      #pragma unroll
      for (int nf = 0; nf < 4; nf++){
        f16x8 k0 = *(const f16x8*)&lK[t][swz(nf*16 + c, g*8)];
        f16x8 k1 = *(const f16x8*)&lK[t][swz(nf*16 + c, 32 + g*8)];
        f32x4 a = f32x4{0,0,0,0};
        a = __builtin_amdgcn_mfma_f32_16x16x32_f16(qf[0], k0, a, 0,0,0);
        a = __builtin_amdgcn_mfma_f32_16x16x32_f16(qf[1], k1, a, 0,0,0);
        #pragma unroll
        for (int r = 0; r < 4; r++){
          float s = a[r];
          float v = __builtin_fabsf(s);
          rm[r] = fmaxf(rm[r], s);
          cnt += (v < lo) ? 1u : 0u;
          if (v >= lo && v < hi){
            int qq = qrow0 + g*4 + r;
            int kk = kt*64 + nf*16 + c;
            unsigned pk = ((unsigned)bh << 22) | ((unsigned)qq << 11) | (unsigned)kk;
            unsigned p = atomicAdd(&lcnt, 1u);
            if (p < 2048u) lbuf[p] = pk;
            else { unsigned gp = atomicAdd(&ctr[0], 1u); if (gp < CAP) candidx[gp] = pk; }
          }
        }
      }
    }
    __syncthreads();
    if (lcnt >= 1024u){
      unsigned cflush = lcnt; if (cflush > 2048u) cflush = 2048u;
      if (tid == 0) gbase = atomicAdd(&ctr[0], cflush);
      __syncthreads();
      for (unsigned i = tid; i < cflush; i += 256){
        unsigned p = gbase + i; if (p < CAP) candidx[p] = lbuf[i];
      }
      __syncthreads();
      if (tid == 0) lcnt = 0u;
    }
  }
  __syncthreads();
  { unsigned cflush = lcnt; if (cflush > 2048u) cflush = 2048u;
    if (tid == 0) gbase = atomicAdd(&ctr[0], cflush);
    __syncthreads();
    for (unsigned i = tid; i < cflush; i += 256){
      unsigned p = gbase + i; if (p < CAP) candidx[p] = lbuf[i];
    }
  }
  #pragma unroll
  for (int r = 0; r < 4; r++){
    float m = rm[r];
    m = fmaxf(m, __shfl_xor(m, 1, 64));
    m = fmaxf(m, __shfl_xor(m, 2, 64));
    m = fmaxf(m, __shfl_xor(m, 4, 64));
    m = fmaxf(m, __shfl_xor(m, 8, 64));
    if (c == 0) rowmax[(size_t)bh * 2048 + qrow0 + g*4 + r] = m;
  }
  #pragma unroll
  for (int d = 1; d < 64; d <<= 1) cnt += __shfl_xor(cnt, d, 64);
  if (lane == 0) atomicAdd(&ctr[1], cnt);
}

// ---- refine: exact f64 score per candidate (one per wave) + fused histogram ----
__global__ __launch_bounds__(256) void refine_k(const u16* __restrict__ qh,
    const u16* __restrict__ ql, const u16* __restrict__ kh, const u16* __restrict__ kl,
    const unsigned* __restrict__ candidx, const unsigned* __restrict__ ctr,
    float* __restrict__ candval, const float* __restrict__ sc,
    unsigned* __restrict__ h2){
  const int lane = threadIdx.x & 63;
  const unsigned gw = blockIdx.x * 4 + (threadIdx.x >> 6);
  const unsigned nw = gridDim.x * 4;
  unsigned n = ctr[0]; if (n > CAP) n = CAP;
  const float lo = sc[0], hi = sc[1];
  const float inv = 8192.0f / (hi - lo);
  for (unsigned i = gw; i < n; i += nw){
    unsigned pk = candidx[i];
    int bh = pk >> 22, q = (pk >> 11) & 2047, k = pk & 2047;
    double s = exact_score(qh, ql, kh, kl, (size_t)bh * (2048*64), q, k, lane);
    if (lane == 0){
      float av = (float)fabs(s);
      candval[i] = av;
      int idx = (int)((av - lo) * inv);
      idx = idx < 0 ? 0 : (idx > 8191 ? 8191 : idx);
      atomicAdd(&h2[idx], 1u);
    }
  }
}

// ---------------- find target bin b, base rank, next non-empty bin (1 block) ----
__global__ __launch_bounds__(256) void scan_b(const unsigned* __restrict__ h2,
    unsigned* __restrict__ ctr){
  __shared__ unsigned bins[8192];
  __shared__ unsigned part[256];
  const int tid = threadIdx.x;
  unsigned s = 0;
  for (int i = 0; i < 32; i++){ unsigned v = h2[tid*32 + i]; bins[tid*32 + i] = v; s += v; }
  part[tid] = s;
  __syncthreads();
  if (tid == 0){
    unsigned n = ctr[0]; if (n > CAP) n = CAP;
    long long r2 = (long long)RANK - (long long)ctr[1];
    if (r2 < 0) r2 = 0;
    if (n > 0 && r2 >= (long long)n) r2 = (long long)n - 1;
    unsigned long long cum = 0; int seg = 0;
    for (; seg < 255; seg++){ if (cum + part[seg] > (unsigned long long)r2) break; cum += part[seg]; }
    int b = seg * 32;
    while (b < 8191 && cum + bins[b] <= (unsigned long long)r2){ cum += bins[b]; b++; }
    int b2 = -1;
    for (int x = b + 1; x < 8192; x++){ if (bins[x]){ b2 = x; break; } }
    ctr[2] = (unsigned)b;
    ctr[3] = (unsigned)cum;
    ctr[4] = (unsigned)r2;
    ctr[5] = (unsigned)(b2 + 1);          // 0 = none
  }
}

// ---------------- extract bin-b and bin-b2 members ----------------
__global__ __launch_bounds__(256) void extract_k(const float* __restrict__ cand,
    unsigned* __restrict__ ctr, const float* __restrict__ sc,
    float* __restrict__ bufB, float* __restrict__ bufB2){
  const int tid = threadIdx.x;
  unsigned n = ctr[0]; if (n > CAP) n = CAP;
  const float lo = sc[0], hi = sc[1];
  const float inv = 8192.0f / (hi - lo);
  const int b = (int)ctr[2];
  const int b2 = (int)ctr[5] - 1;
  const unsigned stride = gridDim.x * 256;
  for (unsigned i = blockIdx.x * 256 + tid; i < n; i += stride){
    float v = cand[i];
    int idx = (int)((v - lo) * inv);
    idx = idx < 0 ? 0 : (idx > 8191 ? 8191 : idx);
    if (idx == b){
      unsigned p = atomicAdd(&ctr[6], 1u);
      if (p < 1024u) bufB[p] = v;
    } else if (idx == b2){
      unsigned p = atomicAdd(&ctr[7], 1u);
      if (p < 1024u) bufB2[p] = v;
    }
  }
}

// ---------------- final: parallel rank-select j-th / (j+1)-th smallest ----------
__global__ __launch_bounds__(256) void final_k(const float* __restrict__ bufB,
    const float* __restrict__ bufB2, const unsigned* __restrict__ ctr,
    float* __restrict__ sc){
  __shared__ float vals[1024];
  __shared__ unsigned rsel0, rsel1, minb2;
  const int tid = threadIdx.x;
  const unsigned mB = ctr[6];
  const float lo = sc[0], hi = sc[1];
  const float binw = (hi - lo) * (1.0f / 8192.0f);
  const int b = (int)ctr[2];
  const long long j = (long long)ctr[4] - (long long)ctr[3];
  if (tid == 0){ rsel0 = 0x7f800000u; rsel1 = 0x7f800000u; minb2 = 0x7f800000u; }
  unsigned m = mB > 1024u ? 1024u : mB;
  for (unsigned i = tid; i < m; i += 256) vals[i] = bufB[i];
  __syncthreads();
  if (mB <= 1024u && m > 0){
    for (unsigned i = tid; i < m; i += 256){
      float v = vals[i]; unsigned rk = 0;
      for (unsigned x = 0; x < m; x++){
        float u = vals[x];
        rk += (u < v) || (u == v && x < i);
      }
      if ((long long)rk == j)     atomicMin(&rsel0, __builtin_bit_cast(unsigned, v));
      if ((long long)rk == j + 1) atomicMin(&rsel1, __builtin_bit_cast(unsigned, v));
    }
  }
  unsigned m2c = ctr[7]; unsigned m2 = m2c > 1024u ? 1024u : m2c;
  for (unsigned i = tid; i < m2; i += 256)
    atomicMin(&minb2, __builtin_bit_cast(unsigned, bufB2[i]));
  __syncthreads();
  if (tid == 0){
    float thr;
    if (mB > 1024u || m == 0 || j < 0 || j >= (long long)m){
      thr = lo + ((float)b + 0.5f) * binw;
    } else {
      float sR = __builtin_bit_cast(float, rsel0);
      float sR1;
      if (j + 1 < (long long)m) sR1 = __builtin_bit_cast(float, rsel1);
      else if (m2 > 0)          sR1 = __builtin_bit_cast(float, minb2);
      else                      sR1 = sR;
      if (!(sR1 < 3.0e38f)) sR1 = sR;
      thr = sR + QFRAC * (sR1 - sR);
    }
    sc[2] = thr;
  }
}

// ---- pass C: flash attention, static-max v_exp softmax, VALU-diet (R17-proven) ----
__global__ __launch_bounds__(256) void attn2_k(
    const u16* __restrict__ qhi, const u16* __restrict__ qlo,
    const u16* __restrict__ khi, const u16* __restrict__ klo,
    const u16* __restrict__ vt, const float* __restrict__ rowmax,
    u16* __restrict__ ohi, const float* __restrict__ sc)
{
  __shared__ u16 lKh[64*64];
  __shared__ u16 lKl[64*64];
  __shared__ u16 lV [64*64];
  __shared__ u16 lP [4*16*64];
  const int tid = threadIdx.x, lane = tid & 63, w = tid >> 6;
  const int g = lane >> 4, c = lane & 15;
  const int wid = (blockIdx.x & 7) * 128 + (blockIdx.x >> 3);   // XCD swizzle
  const int bh = wid >> 5, qt = wid & 31;
  const int qrow0 = qt*64 + w*16;
  const size_t base = (size_t)bh * (2048*64);
  const float thr = sc[2];

  f16x8 qfh[2], qfl[2];
  #pragma unroll
  for (int ks = 0; ks < 2; ks++){
    size_t off = base + (size_t)(qrow0 + c)*64 + ks*32 + g*8;
    qfh[ks] = *(const f16x8*)&qhi[off];
    qfl[ks] = *(const f16x8*)&qlo[off];
  }
  float mh[4];
  #pragma unroll
  for (int r = 0; r < 4; r++)
    mh[r] = rowmax[(size_t)bh * 2048 + qrow0 + g*4 + r];

  f16x8 vones;
  #pragma unroll
  for (int j = 0; j < 8; j++) vones[j] = (_Float16)1.0f;

  f32x4 O[4];
  f32x4 zacc = f32x4{0.f, 0.f, 0.f, 0.f};      // z via ones-MFMA (all 16 c-lanes hold row z)
  #pragma unroll
  for (int j = 0; j < 4; j++) O[j] = f32x4{0,0,0,0};

  for (int kt = 0; kt < 32; kt++){
    __syncthreads();
    #pragma unroll
    for (int i = 0; i < 2; i++){
      int ch = tid + i*256, row = ch >> 3, c8 = ch & 7;
      int di = swz(row, c8*8);
      size_t go = base + (size_t)(kt*64 + row)*64 + c8*8;
      *(uint4*)&lKh[di] = *(const uint4*)&khi[go];
      *(uint4*)&lKl[di] = *(const uint4*)&klo[go];
      size_t gv = base + (size_t)row * 2048 + kt*64 + c8*8;
      *(uint4*)&lV [di] = *(const uint4*)&vt[gv];
    }
    __syncthreads();

    f16x8 kfh[4][2], kfl[4][2];
    #pragma unroll
    for (int nf = 0; nf < 4; nf++)
      #pragma unroll
      for (int ks = 0; ks < 2; ks++){
        int off = swz(nf*16 + c, ks*32 + g*8);
        kfh[nf][ks] = *(const f16x8*)&lKh[off];
        kfl[nf][ks] = *(const f16x8*)&lKl[off];
      }

    f32x4 sa[4];
    __builtin_amdgcn_s_setprio(1);
    #pragma unroll
    for (int nf = 0; nf < 4; nf++){
      f32x4 a = f32x4{0,0,0,0};
      #pragma unroll
      for (int ks = 0; ks < 2; ks++){
        a = __builtin_amdgcn_mfma_f32_16x16x32_f16(qfh[ks], kfh[nf][ks], a, 0,0,0);
        a = __builtin_amdgcn_mfma_f32_16x16x32_f16(qfh[ks], kfl[nf][ks], a, 0,0,0);
        a = __builtin_amdgcn_mfma_f32_16x16x32_f16(qfl[ks], kfh[nf][ks], a, 0,0,0);
      }
      sa[nf] = a;                          // s2 space (q pre-scaled by 0.125/ln2)
    }
    __builtin_amdgcn_s_setprio(0);

    // mask: shared d = |s|-thr feeds keep test and (deferred) band test
    bool keep[4][4];
    float mind = 1e30f;
    #pragma unroll
    for (int nf = 0; nf < 4; nf++)
      #pragma unroll
      for (int r = 0; r < 4; r++){
        float d = __builtin_fabsf(sa[nf][r]) - thr;
        keep[nf][r] = (d >= 0.f);
        mind = fminf(mind, __builtin_fabsf(d));
      }
    if (__any(mind < EPS_REF)){            // rare: re-arbitrate boundary scores exactly
      #pragma unroll
      for (int nf = 0; nf < 4; nf++)
        #pragma unroll
        for (int r = 0; r < 4; r++){
          unsigned long long bal = __ballot(
              __builtin_fabsf(__builtin_fabsf(sa[nf][r]) - thr) < EPS_REF);
          while (bal){
            int L = (int)__ffsll((unsigned long long)bal) - 1; bal &= bal - 1;
            int qq = qrow0 + ((L >> 4) << 2) + r;
            int kk = kt*64 + nf*16 + (L & 15);
            double s = exact_score(qhi, qlo, khi, klo, base, qq, kk, lane);
            bool kp = ((float)fabs(s)) >= thr;
            if (lane == L) keep[nf][r] = kp;
          }
        }
    }

    #pragma unroll
    for (int nf = 0; nf < 4; nf++)
      #pragma unroll
      for (int r = 0; r < 4; r++){
        u16 ph = f2h(__builtin_amdgcn_exp2f(sa[nf][r] - mh[r]));
        ph = keep[nf][r] ? ph : (u16)0;
        int prow = g*4 + r;
        lP[(w << 10) + (prow << 6) + ((nf*16 + c) ^ ((prow & 7) << 3))] = ph;
      }

    // lP is wave-private (same-wave write->read; compiler orders LDS ops)
    f16x8 pa[2], vb[4][2];
    #pragma unroll
    for (int ks = 0; ks < 2; ks++)
      pa[ks] = *(const f16x8*)&lP[(w << 10) + (c << 6) + ((ks*32 + g*8) ^ ((c & 7) << 3))];
    #pragma unroll
    for (int nf = 0; nf < 4; nf++)
      #pragma unroll
      for (int ks = 0; ks < 2; ks++)
        vb[nf][ks] = *(const f16x8*)&lV[swz(nf*16 + c, ks*32 + g*8)];
    __builtin_amdgcn_s_setprio(1);
    #pragma unroll
    for (int ks = 0; ks < 2; ks++)
      zacc = __builtin_amdgcn_mfma_f32_16x16x32_f16(pa[ks], vones, zacc, 0,0,0);
    #pragma unroll
    for (int nf = 0; nf < 4; nf++)
      #pragma unroll
      for (int ks = 0; ks < 2; ks++)
        O[nf] = __builtin_amdgcn_mfma_f32_16x16x32_f16(pa[ks], vb[nf][ks], O[nf], 0,0,0);
    __builtin_amdgcn_s_setprio(0);
  }

  const int b = bh >> 4, h = bh & 15;
  #pragma unroll
  for (int r = 0; r < 4; r++){
    float z = zacc[r];                     // identical across the 16 c-lanes of this row
    float inv = (z > 0.f) ? (1.0f / z) : 0.f;
    int srow = qrow0 + g*4 + r;
    #pragma unroll
    for (int nf = 0; nf < 4; nf++){
      float v = O[nf][r] * inv;
      int d = nf*16 + c;
      size_t idx = ((size_t)(b*2048 + srow)) * 1024 + h*64 + d;
      ohi[idx] = f2h(v);
    }
  }
}

// ---------------- host ----------------
extern "C" void kernel_launch(void* const* d_in, const int* in_sizes, int n_in,
                              void* d_out, int out_size, void* d_ws, size_t ws_size,
                              hipStream_t stream)
{
  const float* x  = (const float*)d_in[0];
  const float* Wq = (const float*)d_in[1];
  const float* Wk = (const float*)d_in[2];
  const float* Wv = (const float*)d_in[3];
  const float* Wo = (const float*)d_in[4];

  char* p = (char*)d_ws;
  auto alloc = [&](size_t bytes) -> char* {
    char* r = p; p += (bytes + 255) & ~(size_t)255; return r;
  };
  const size_t NX = 4194304, NW = 1048576;
  u16* xh  = (u16*)alloc(NX*2); u16* xl  = (u16*)alloc(NX*2);
  u16* wqh = (u16*)alloc(NW*2); u16* wql = (u16*)alloc(NW*2);
  u16* wkh = (u16*)alloc(NW*2); u16* wkl = (u16*)alloc(NW*2);
  u16* wvh = (u16*)alloc(NW*2);
  u16* woh = (u16*)alloc(NW*2);
  u16* qh  = (u16*)alloc(NX*2); u16* ql  = (u16*)alloc(NX*2);
  u16* kh  = (u16*)alloc(NX*2); u16* kl  = (u16*)alloc(NX*2);
  u16* vth = (u16*)alloc(NX*2);
  u16* oh  = (u16*)alloc(NX*2); u16* ol  = (u16*)alloc(NX*2);
  float*    rowmax = (float*)alloc(65536*4);    // [B*H][S]
  unsigned* histc = (unsigned*)alloc(8192*4);
  unsigned* hist2 = (unsigned*)alloc(8192*4);
  unsigned* ctr   = (unsigned*)alloc(256);
  float*    sc    = (float*)alloc(256);
  float*    bufB  = (float*)alloc(1024*4);
  float*    bufB2 = (float*)alloc(1024*4);
  if ((size_t)(p - (char*)d_ws) > ws_size) return;
  unsigned* candidx = (unsigned*)oh;            // alias: dead before oh written
  float*    candval = (float*)ol;               // alias: ol otherwise unused now

  hipMemsetAsync(histc, 0, 8192*4*2 + 256 + 256, stream);   // histc+hist2+ctr+sc

  dim3 gb(256);
  split_all<<<dim3(2048), gb, 0, stream>>>(x, Wq, Wk, Wv, Wo,
      xh, xl, wqh, wql, wkh, wkl, wvh, woh);

  gemm_projQKV<<<dim3(48, 32), gb, 0, stream>>>(xh, xl, wqh, wql, wkh, wkl, wvh,
                                                qh, ql, kh, kl, vth);

  hist_sub   <<<dim3(256),  gb, 0, stream>>>(qh, kh, histc);
  scan_window<<<dim3(1),    gb, 0, stream>>>(histc, sc);
  collect_k  <<<dim3(1024), gb, 0, stream>>>(qh, kh, sc, candidx, ctr, rowmax);
  refine_k   <<<dim3(2048), gb, 0, stream>>>(qh, ql, kh, kl, candidx, ctr, candval, sc, hist2);
  scan_b     <<<dim3(1),    gb, 0, stream>>>(hist2, ctr);
  extract_k  <<<dim3(64),   gb, 0, stream>>>(candval, ctr, sc, bufB, bufB2);
  final_k    <<<dim3(1),    gb, 0, stream>>>(bufB, bufB2, ctr, sc);
  attn2_k    <<<dim3(1024), gb, 0, stream>>>(qh, ql, kh, kl, vth, rowmax, oh, sc);

  gemm_out<<<dim3(16, 64), gb, 0, stream>>>(oh, woh, (float*)d_out);
}

// Round 22
// 418.187 us; speedup vs baseline: 1.0383x; 1.0383x over previous
//
#include <hip/hip_runtime.h>
#include <stdint.h>

typedef float f32x4 __attribute__((ext_vector_type(4)));
typedef _Float16 f16x8 __attribute__((ext_vector_type(8)));
typedef unsigned short u16;

#define DEVI static __device__ __forceinline__

DEVI u16 f2h(float f){ _Float16 h = (_Float16)f; return __builtin_bit_cast(u16, h); }
DEVI float h2f(u16 b){ return (float)__builtin_bit_cast(_Float16, b); }
// XOR-swizzled u16 index into a [rows][64] u16 LDS tile (row pitch 128B) — proven 0-conflict (R5).
DEVI int swz(int row, int col){ return (row << 6) + (col ^ ((row & 7) << 3)); }

static constexpr unsigned RANK = 120795954u;   // floor(0.9 * (2*16*2048*2048 - 1))
static constexpr float QFRAC = 0.3f;           // frac part of 0.9*(n-1)
static constexpr float CW = 1.0f / 512.0f;     // coarse bin width over [0,16) (s2 space)
static constexpr unsigned CAP = 1u << 20;      // candidate slots
static constexpr float EPS_REF = 6e-6f;        // boundary band (s2 space)
static constexpr float QSCALE = 0.18033688011112042f;  // 0.125/ln2 folded into stored q

// ---------------- fused split: all 5 inputs -> f16 hi (+ lo where needed) ----------
__global__ __launch_bounds__(256) void split_all(
    const float* __restrict__ x,  const float* __restrict__ wq,
    const float* __restrict__ wk, const float* __restrict__ wv,
    const float* __restrict__ wo,
    u16* __restrict__ xh,  u16* __restrict__ xl,
    u16* __restrict__ wqh, u16* __restrict__ wql,
    u16* __restrict__ wkh, u16* __restrict__ wkl,
    u16* __restrict__ wvh, u16* __restrict__ woh)
{
  const int stride = gridDim.x * 256;
  for (int i = blockIdx.x * 256 + threadIdx.x; i < 2097152; i += stride){
    const float* src; u16* hi; u16* lo; int off;
    if (i < 1048576)      { src = x;  hi = xh;  lo = xl;  off = i; }
    else if (i < 1310720) { src = wq; hi = wqh; lo = wql; off = i - 1048576; }
    else if (i < 1572864) { src = wk; hi = wkh; lo = wkl; off = i - 1310720; }
    else if (i < 1835008) { src = wv; hi = wvh; lo = nullptr; off = i - 1572864; }
    else                  { src = wo; hi = woh; lo = nullptr; off = i - 1835008; }
    float4 v = ((const float4*)src)[off];
    u16 h0 = f2h(v.x), h1 = f2h(v.y), h2 = f2h(v.z), h3 = f2h(v.w);
    ((ushort4*)hi)[off] = make_ushort4(h0, h1, h2, h3);
    if (lo)
      ((ushort4*)lo)[off] = make_ushort4(f2h(v.x - h2f(h0)), f2h(v.y - h2f(h1)),
                                         f2h(v.z - h2f(h2)), f2h(v.w - h2f(h3)));
  }
}

// ---- fused Q+K+V projection GEMM, single launch (48x32 grid, 2-wave packing) ------
// which = blockIdx.x>>4: 0=Q (3-term, *QSCALE, hi/lo), 1=K (3-term, hi/lo),
// 2=V (1-term hi-only, transposed store). Top-level block-uniform branch; each body
// is internally branch-free (R14 lesson: no per-iteration conditionals).
__global__ __launch_bounds__(256) void gemm_projQKV(
    const u16* __restrict__ Ah, const u16* __restrict__ Al,
    const u16* __restrict__ wqh, const u16* __restrict__ wql,
    const u16* __restrict__ wkh, const u16* __restrict__ wkl,
    const u16* __restrict__ wvh,
    u16* __restrict__ qh, u16* __restrict__ ql,
    u16* __restrict__ kh, u16* __restrict__ kl, u16* __restrict__ vth)
{
  __shared__ u16 lAh[128*64], lAl[128*64];
  __shared__ u16 lBh[64*64],  lBl[64*64];
  const int tid = threadIdx.x;
  const int which = blockIdx.x >> 4;
  const int m0 = blockIdx.y * 128, n0 = (blockIdx.x & 15) * 64;
  const int lane = tid & 63, w = tid >> 6;
  const int wm = w >> 1, wn = w & 1;
  const int g = lane >> 4, c = lane & 15;

  if (which == 2){
    // ---------------- V body: 1-term hi-only, transposed store ----------------
    f32x4 acc[4][2];
    #pragma unroll
    for (int i = 0; i < 4; i++)
      #pragma unroll
      for (int j = 0; j < 2; j++) acc[i][j] = f32x4{0,0,0,0};

    for (int k0 = 0; k0 < 1024; k0 += 64){
      __syncthreads();
      #pragma unroll
      for (int i = 0; i < 4; i++){
        int ch = tid + i*256, row = ch >> 3, c8 = ch & 7;
        *(uint4*)&lAh[swz(row, c8*8)] = *(const uint4*)&Ah[(size_t)(m0 + row) * 1024 + k0 + c8*8];
      }
      #pragma unroll
      for (int i = 0; i < 2; i++){
        int ch = tid + i*256, row = ch >> 3, c8 = ch & 7;
        *(uint4*)&lBh[swz(row, c8*8)] = *(const uint4*)&wvh[(size_t)(n0 + row) * 1024 + k0 + c8*8];
      }
      __syncthreads();
      f16x8 ah[4][2], bh[2][2];
      #pragma unroll
      for (int mf = 0; mf < 4; mf++)
        #pragma unroll
        for (int ks = 0; ks < 2; ks++)
          ah[mf][ks] = *(const f16x8*)&lAh[swz(wm*64 + mf*16 + c, ks*32 + g*8)];
      #pragma unroll
      for (int nf = 0; nf < 2; nf++)
        #pragma unroll
        for (int ks = 0; ks < 2; ks++)
          bh[nf][ks] = *(const f16x8*)&lBh[swz(wn*32 + nf*16 + c, ks*32 + g*8)];
      __builtin_amdgcn_s_setprio(1);
      #pragma unroll
      for (int mf = 0; mf < 4; mf++)
        #pragma unroll
        for (int nf = 0; nf < 2; nf++)
          #pragma unroll
          for (int ks = 0; ks < 2; ks++)
            acc[mf][nf] = __builtin_amdgcn_mfma_f32_16x16x32_f16(ah[mf][ks], bh[nf][ks], acc[mf][nf], 0,0,0);
      __builtin_amdgcn_s_setprio(0);
    }
    #pragma unroll
    for (int mf = 0; mf < 4; mf++)
      #pragma unroll
      for (int nf = 0; nf < 2; nf++)
        #pragma unroll
        for (int r = 0; r < 4; r++){
          int m = m0 + wm*64 + mf*16 + g*4 + r;
          int n = n0 + wn*32 + nf*16 + c;
          int b = m >> 11, s = m & 2047, h = n >> 6, d = n & 63;
          size_t idx = (((size_t)(b*16 + h)) * 64 + d) * 2048 + s;
          vth[idx] = f2h(acc[mf][nf][r]);
        }
    return;
  }

  // ---------------- Q/K body: 3-term, branch-free inner loops ----------------
  const u16* __restrict__ Bh = which == 0 ? wqh : wkh;
  const u16* __restrict__ Bl = which == 0 ? wql : wkl;
  f32x4 acc[4][2];
  #pragma unroll
  for (int i = 0; i < 4; i++)
    #pragma unroll
    for (int j = 0; j < 2; j++) acc[i][j] = f32x4{0,0,0,0};

  for (int k0 = 0; k0 < 1024; k0 += 64){
    __syncthreads();
    #pragma unroll
    for (int i = 0; i < 4; i++){                     // A: 128 rows x 64 u16
      int ch = tid + i*256, row = ch >> 3, c8 = ch & 7;
      int di = swz(row, c8*8);
      size_t ga = (size_t)(m0 + row) * 1024 + k0 + c8*8;
      *(uint4*)&lAh[di] = *(const uint4*)&Ah[ga];
      *(uint4*)&lAl[di] = *(const uint4*)&Al[ga];
    }
    #pragma unroll
    for (int i = 0; i < 2; i++){                     // B: 64 rows x 64 u16
      int ch = tid + i*256, row = ch >> 3, c8 = ch & 7;
      int di = swz(row, c8*8);
      size_t gb = (size_t)(n0 + row) * 1024 + k0 + c8*8;
      *(uint4*)&lBh[di] = *(const uint4*)&Bh[gb];
      *(uint4*)&lBl[di] = *(const uint4*)&Bl[gb];
    }
    __syncthreads();
    f16x8 ah[4][2], al[4][2], bh[2][2], bl[2][2];
    #pragma unroll
    for (int mf = 0; mf < 4; mf++)
      #pragma unroll
      for (int ks = 0; ks < 2; ks++){
        int off = swz(wm*64 + mf*16 + c, ks*32 + g*8);
        ah[mf][ks] = *(const f16x8*)&lAh[off];
        al[mf][ks] = *(const f16x8*)&lAl[off];
      }
    #pragma unroll
    for (int nf = 0; nf < 2; nf++)
      #pragma unroll
      for (int ks = 0; ks < 2; ks++){
        int off = swz(wn*32 + nf*16 + c, ks*32 + g*8);
        bh[nf][ks] = *(const f16x8*)&lBh[off];
        bl[nf][ks] = *(const f16x8*)&lBl[off];
      }
    __builtin_amdgcn_s_setprio(1);
    #pragma unroll
    for (int mf = 0; mf < 4; mf++)
      #pragma unroll
      for (int nf = 0; nf < 2; nf++)
        #pragma unroll
        for (int ks = 0; ks < 2; ks++){
          acc[mf][nf] = __builtin_amdgcn_mfma_f32_16x16x32_f16(ah[mf][ks], bh[nf][ks], acc[mf][nf], 0,0,0);
          acc[mf][nf] = __builtin_amdgcn_mfma_f32_16x16x32_f16(ah[mf][ks], bl[nf][ks], acc[mf][nf], 0,0,0);
          acc[mf][nf] = __builtin_amdgcn_mfma_f32_16x16x32_f16(al[mf][ks], bh[nf][ks], acc[mf][nf], 0,0,0);
        }
    __builtin_amdgcn_s_setprio(0);
  }
  #pragma unroll
  for (int mf = 0; mf < 4; mf++)
    #pragma unroll
    for (int nf = 0; nf < 2; nf++)
      #pragma unroll
      for (int r = 0; r < 4; r++){
        int m = m0 + wm*64 + mf*16 + g*4 + r;
        int n = n0 + wn*32 + nf*16 + c;
        float v = acc[mf][nf][r];
        int b = m >> 11, s = m & 2047, h = n >> 6, d = n & 63;
        size_t idx = (((size_t)(b*16 + h)) * 2048 + s) * 64 + d;
        if (which == 0){
          v *= QSCALE;                          // fold 0.125/ln2 into stored q
          u16 hv = f2h(v);
          qh[idx] = hv; ql[idx] = f2h(v - h2f(hv));
        } else {
          u16 hv = f2h(v);
          kh[idx] = hv; kl[idx] = f2h(v - h2f(hv));
        }
      }
}

// ---- output projection GEMM: hi-only 1-term, 64x64 tiles (1024 blocks, 4/CU) ------
__global__ __launch_bounds__(256) void gemm_out(
    const u16* __restrict__ Ahi, const u16* __restrict__ Bhi,
    float* __restrict__ out)
{
  __shared__ u16 lAh[64*64];
  __shared__ u16 lBh[64*64];
  const int tid = threadIdx.x;
  const int m0 = blockIdx.y * 64, n0 = blockIdx.x * 64;
  const int lane = tid & 63, w = tid >> 6;
  const int wm = w >> 1, wn = w & 1;
  const int g = lane >> 4, c = lane & 15;
  f32x4 acc[2][2];
  #pragma unroll
  for (int i = 0; i < 2; i++)
    #pragma unroll
    for (int j = 0; j < 2; j++) acc[i][j] = f32x4{0,0,0,0};

  for (int k0 = 0; k0 < 1024; k0 += 64){
    __syncthreads();
    #pragma unroll
    for (int i = 0; i < 2; i++){
      int ch = tid + i*256, row = ch >> 3, c8 = ch & 7;
      *(uint4*)&lAh[swz(row, c8*8)] = *(const uint4*)&Ahi[(size_t)(m0 + row) * 1024 + k0 + c8*8];
    }
    #pragma unroll
    for (int i = 0; i < 2; i++){
      int ch = tid + i*256, row = ch >> 3, c8 = ch & 7;
      *(uint4*)&lBh[swz(row, c8*8)] = *(const uint4*)&Bhi[(size_t)(n0 + row) * 1024 + k0 + c8*8];
    }
    __syncthreads();
    f16x8 ah[2][2], bh[2][2];
    #pragma unroll
    for (int mf = 0; mf < 2; mf++)
      #pragma unroll
      for (int ks = 0; ks < 2; ks++)
        ah[mf][ks] = *(const f16x8*)&lAh[swz(wm*32 + mf*16 + c, ks*32 + g*8)];
    #pragma unroll
    for (int nf = 0; nf < 2; nf++)
      #pragma unroll
      for (int ks = 0; ks < 2; ks++)
        bh[nf][ks] = *(const f16x8*)&lBh[swz(wn*32 + nf*16 + c, ks*32 + g*8)];
    __builtin_amdgcn_s_setprio(1);
    #pragma unroll
    for (int mf = 0; mf < 2; mf++)
      #pragma unroll
      for (int nf = 0; nf < 2; nf++)
        #pragma unroll
        for (int ks = 0; ks < 2; ks++)
          acc[mf][nf] = __builtin_amdgcn_mfma_f32_16x16x32_f16(ah[mf][ks], bh[nf][ks], acc[mf][nf], 0,0,0);
    __builtin_amdgcn_s_setprio(0);
  }
  #pragma unroll
  for (int mf = 0; mf < 2; mf++)
    #pragma unroll
    for (int nf = 0; nf < 2; nf++)
      #pragma unroll
      for (int r = 0; r < 4; r++){
        int m = m0 + wm*32 + mf*16 + g*4 + r;
        int n = n0 + wn*32 + nf*16 + c;
        out[(size_t)m * 1024 + n] = acc[mf][nf][r];
      }
}

// ------- exact f64 score (s2 space) of stored q*,k — bit-identical everywhere -------
DEVI double exact_score(const u16* __restrict__ qh, const u16* __restrict__ ql,
                        const u16* __restrict__ kh, const u16* __restrict__ kl,
                        size_t base, int q, int k, int lane){
  size_t qo = base + (size_t)q * 64 + lane;
  size_t ko = base + (size_t)k * 64 + lane;
  double qd = (double)h2f(qh[qo]) + (double)h2f(ql[qo]);
  double kd = (double)h2f(kh[ko]) + (double)h2f(kl[ko]);
  double p = qd * kd;
  #pragma unroll
  for (int d = 1; d < 64; d <<= 1) p += __shfl_xor(p, d, 64);
  return p;
}

// ------ pass A: subsampled coarse histogram (f16-hi QK, s2 space), kt-split x4 ------
__global__ __launch_bounds__(256) void hist_sub(const u16* __restrict__ qh,
    const u16* __restrict__ kh, unsigned* __restrict__ ghist){
  __shared__ u16 lK[64*64];
  __shared__ unsigned lh[8192];
  const int tid = threadIdx.x, lane = tid & 63, w = tid >> 6;
  const int g = lane >> 4, c = lane & 15;
  const int bh = blockIdx.x >> 3, rem = blockIdx.x & 7;
  const int qt = rem & 1, quarter = rem >> 1;
  const int qrow0 = qt*64 + w*16;
  const size_t base = (size_t)bh * (2048*64);
  #pragma unroll
  for (int i = 0; i < 32; i++) lh[tid + i*256] = 0u;
  f16x8 qf[2];
  #pragma unroll
  for (int ks = 0; ks < 2; ks++)
    qf[ks] = *(const f16x8*)&qh[base + (size_t)(qrow0 + c)*64 + ks*32 + g*8];

  const int kt0 = quarter * 8;
  for (int kt = kt0; kt < kt0 + 8; kt++){
    __syncthreads();
    #pragma unroll
    for (int i = 0; i < 2; i++){
      int ch = tid + i*256, row = ch >> 3, c8 = ch & 7;
      *(uint4*)&lK[swz(row, c8*8)] = *(const uint4*)&kh[base + (size_t)(kt*64 + row)*64 + c8*8];
    }
    __syncthreads();
    #pragma unroll
    for (int nf = 0; nf < 4; nf++){
      f16x8 k0 = *(const f16x8*)&lK[swz(nf*16 + c, g*8)];
      f16x8 k1 = *(const f16x8*)&lK[swz(nf*16 + c, 32 + g*8)];
      f32x4 a = f32x4{0,0,0,0};
      a = __builtin_amdgcn_mfma_f32_16x16x32_f16(qf[0], k0, a, 0,0,0);
      a = __builtin_amdgcn_mfma_f32_16x16x32_f16(qf[1], k1, a, 0,0,0);
      #pragma unroll
      for (int r = 0; r < 4; r++){
        float v = __builtin_fabsf(a[r]);
        int idx = (int)fminf(v * 512.f, 8191.f);
        atomicAdd(&lh[idx], 1u);
      }
    }
  }
  __syncthreads();
  #pragma unroll
  for (int i = 0; i < 32; i++){
    unsigned cnt = lh[tid + i*256];
    if (cnt) atomicAdd(&ghist[tid + i*256], cnt);
  }
}

// ---------------- window scan (1 block) ----------------
__global__ __launch_bounds__(256) void scan_window(const unsigned* __restrict__ ghist,
    float* __restrict__ sc){
  __shared__ unsigned bins[8192];
  __shared__ unsigned part[256];
  int tid = threadIdx.x;
  unsigned s = 0;
  for (int i = 0; i < 32; i++){ unsigned v = ghist[tid*32 + i]; bins[tid*32 + i] = v; s += v; }
  part[tid] = s;
  __syncthreads();
  if (tid == 0){
    unsigned long long total = 0;
    for (int i = 0; i < 256; i++) total += part[i];
    unsigned long long target = (unsigned long long)(0.9 * (double)total);
    unsigned long long cum = 0; int seg = 0;
    for (; seg < 255; seg++){ if (cum + part[seg] > target) break; cum += part[seg]; }
    int b = seg * 32;
    while (b < 8191 && cum + bins[b] <= target){ cum += bins[b]; b++; }
    int blo = b - 4; if (blo < 0) blo = 0;
    int bhi = b + 5; if (bhi > 8191) bhi = 8191;
    sc[0] = (float)blo * CW;
    sc[1] = (float)bhi * CW;
  }
}

// ---- pass B (R5 structure + 2-kt staging): LDS-staged K, block buffer, rowmax ----
__global__ __launch_bounds__(256) void collect_k(const u16* __restrict__ qh,
    const u16* __restrict__ kh, const float* __restrict__ sc,
    unsigned* __restrict__ candidx, unsigned* __restrict__ ctr,
    float* __restrict__ rowmax){
  __shared__ u16 lK[2][64*64];                  // 16 KB: two K-tiles per barrier pair
  __shared__ unsigned lbuf[4096];
  __shared__ unsigned lcnt, gbase;
  const int tid = threadIdx.x, lane = tid & 63, w = tid >> 6;
  const int g = lane >> 4, c = lane & 15;
  const int wid = (blockIdx.x & 7) * 128 + (blockIdx.x >> 3);   // XCD swizzle (1024)
  const int bh = wid >> 5, qt = wid & 31;
  const int qrow0 = qt*64 + w*16;
  const size_t base = (size_t)bh * (2048*64);
  const float lo = sc[0], hi = sc[1];
  if (tid == 0) lcnt = 0u;
  f16x8 qf[2];
  #pragma unroll
  for (int ks = 0; ks < 2; ks++)
    qf[ks] = *(const f16x8*)&qh[base + (size_t)(qrow0 + c)*64 + ks*32 + g*8];
  unsigned cnt = 0;
  float rm[4] = {-1e30f, -1e30f, -1e30f, -1e30f};

  for (int kt2 = 0; kt2 < 16; kt2++){
    __syncthreads();
    #pragma unroll
    for (int t = 0; t < 2; t++)
      #pragma unroll
      for (int i = 0; i < 2; i++){
        int ch = tid + i*256, row = ch >> 3, c8 = ch & 7;
        *(uint4*)&lK[t][swz(row, c8*8)] =
            *(const uint4*)&kh[base + (size_t)((kt2*2 + t)*64 + row)*64 + c8*8];
      }
    __syncthreads();
    #pragma unroll
    for (int t = 0; t < 2; t++){
      const int kt = kt2*2 + t;
      #pragma unroll
      for (int nf = 0; nf < 4; nf++){
        f16x8 k0 = *(const f16x8*)&lK[t][swz(nf*16 + c, g*8)];
        f16x8 k1 = *(const f16x8*)&lK[t][swz(nf*16 + c, 32 + g*8)];
        f32x4 a = f32x4{0,0,0,0};
        a = __builtin_amdgcn_mfma_f32_16x16x32_f16(qf[0], k0, a, 0,0,0);
        a = __builtin_amdgcn_mfma_f32_16x16x32_f16(qf[1], k1, a, 0,0,0);
        #pragma unroll
        for (int r = 0; r < 4; r++){
          float s = a[r];
          float v = __builtin_fabsf(s);
          rm[r] = fmaxf(rm[r], s);
          cnt += (v < lo) ? 1u : 0u;
          if (v >= lo && v < hi){
            int qq = qrow0 + g*4 + r;
            int kk = kt*64 + nf*16 + c;
            unsigned pk = ((unsigned)bh << 22) | ((unsigned)qq << 11) | (unsigned)kk;
            unsigned p = atomicAdd(&lcnt, 1u);
            if (p < 4096u) lbuf[p] = pk;
            else { unsigned gp = atomicAdd(&ctr[0], 1u); if (gp < CAP) candidx[gp] = pk; }
          }
        }
      }
    }
    __syncthreads();
    if (lcnt >= 2048u){
      unsigned cflush = lcnt; if (cflush > 4096u) cflush = 4096u;
      if (tid == 0) gbase = atomicAdd(&ctr[0], cflush);
      __syncthreads();
      for (unsigned i = tid; i < cflush; i += 256){
        unsigned p = gbase + i; if (p < CAP) candidx[p] = lbuf[i];
      }
      __syncthreads();
      if (tid == 0) lcnt = 0u;
    }
  }
  __syncthreads();
  { unsigned cflush = lcnt; if (cflush > 4096u) cflush = 4096u;
    if (tid == 0) gbase = atomicAdd(&ctr[0], cflush);
    __syncthreads();
    for (unsigned i = tid; i < cflush; i += 256){
      unsigned p = gbase + i; if (p < CAP) candidx[p] = lbuf[i];
    }
  }
  #pragma unroll
  for (int r = 0; r < 4; r++){
    float m = rm[r];
    m = fmaxf(m, __shfl_xor(m, 1, 64));
    m = fmaxf(m, __shfl_xor(m, 2, 64));
    m = fmaxf(m, __shfl_xor(m, 4, 64));
    m = fmaxf(m, __shfl_xor(m, 8, 64));
    if (c == 0) rowmax[(size_t)bh * 2048 + qrow0 + g*4 + r] = m;
  }
  #pragma unroll
  for (int d = 1; d < 64; d <<= 1) cnt += __shfl_xor(cnt, d, 64);
  if (lane == 0) atomicAdd(&ctr[1], cnt);
}

// ---- refine: exact f64 score per candidate (one per wave) + fused histogram ----
__global__ __launch_bounds__(256) void refine_k(const u16* __restrict__ qh,
    const u16* __restrict__ ql, const u16* __restrict__ kh, const u16* __restrict__ kl,
    const unsigned* __restrict__ candidx, const unsigned* __restrict__ ctr,
    float* __restrict__ candval, const float* __restrict__ sc,
    unsigned* __restrict__ h2){
  const int lane = threadIdx.x & 63;
  const unsigned gw = blockIdx.x * 4 + (threadIdx.x >> 6);
  const unsigned nw = gridDim.x * 4;
  unsigned n = ctr[0]; if (n > CAP) n = CAP;
  const float lo = sc[0], hi = sc[1];
  const float inv = 8192.0f / (hi - lo);
  for (unsigned i = gw; i < n; i += nw){
    unsigned pk = candidx[i];
    int bh = pk >> 22, q = (pk >> 11) & 2047, k = pk & 2047;
    double s = exact_score(qh, ql, kh, kl, (size_t)bh * (2048*64), q, k, lane);
    if (lane == 0){
      float av = (float)fabs(s);
      candval[i] = av;
      int idx = (int)((av - lo) * inv);
      idx = idx < 0 ? 0 : (idx > 8191 ? 8191 : idx);
      atomicAdd(&h2[idx], 1u);
    }
  }
}

// ---------------- find target bin b, base rank, next non-empty bin (1 block) ----
__global__ __launch_bounds__(256) void scan_b(const unsigned* __restrict__ h2,
    unsigned* __restrict__ ctr){
  __shared__ unsigned bins[8192];
  __shared__ unsigned part[256];
  const int tid = threadIdx.x;
  unsigned s = 0;
  for (int i = 0; i < 32; i++){ unsigned v = h2[tid*32 + i]; bins[tid*32 + i] = v; s += v; }
  part[tid] = s;
  __syncthreads();
  if (tid == 0){
    unsigned n = ctr[0]; if (n > CAP) n = CAP;
    long long r2 = (long long)RANK - (long long)ctr[1];
    if (r2 < 0) r2 = 0;
    if (n > 0 && r2 >= (long long)n) r2 = (long long)n - 1;
    unsigned long long cum = 0; int seg = 0;
    for (; seg < 255; seg++){ if (cum + part[seg] > (unsigned long long)r2) break; cum += part[seg]; }
    int b = seg * 32;
    while (b < 8191 && cum + bins[b] <= (unsigned long long)r2){ cum += bins[b]; b++; }
    int b2 = -1;
    for (int x = b + 1; x < 8192; x++){ if (bins[x]){ b2 = x; break; } }
    ctr[2] = (unsigned)b;
    ctr[3] = (unsigned)cum;
    ctr[4] = (unsigned)r2;
    ctr[5] = (unsigned)(b2 + 1);          // 0 = none
  }
}

// ---------------- extract bin-b and bin-b2 members ----------------
__global__ __launch_bounds__(256) void extract_k(const float* __restrict__ cand,
    unsigned* __restrict__ ctr, const float* __restrict__ sc,
    float* __restrict__ bufB, float* __restrict__ bufB2){
  const int tid = threadIdx.x;
  unsigned n = ctr[0]; if (n > CAP) n = CAP;
  const float lo = sc[0], hi = sc[1];
  const float inv = 8192.0f / (hi - lo);
  const int b = (int)ctr[2];
  const int b2 = (int)ctr[5] - 1;
  const unsigned stride = gridDim.x * 256;
  for (unsigned i = blockIdx.x * 256 + tid; i < n; i += stride){
    float v = cand[i];
    int idx = (int)((v - lo) * inv);
    idx = idx < 0 ? 0 : (idx > 8191 ? 8191 : idx);
    if (idx == b){
      unsigned p = atomicAdd(&ctr[6], 1u);
      if (p < 1024u) bufB[p] = v;
    } else if (idx == b2){
      unsigned p = atomicAdd(&ctr[7], 1u);
      if (p < 1024u) bufB2[p] = v;
    }
  }
}

// ---------------- final: parallel rank-select j-th / (j+1)-th smallest ----------
__global__ __launch_bounds__(256) void final_k(const float* __restrict__ bufB,
    const float* __restrict__ bufB2, const unsigned* __restrict__ ctr,
    float* __restrict__ sc){
  __shared__ float vals[1024];
  __shared__ unsigned rsel0, rsel1, minb2;
  const int tid = threadIdx.x;
  const unsigned mB = ctr[6];
  const float lo = sc[0], hi = sc[1];
  const float binw = (hi - lo) * (1.0f / 8192.0f);
  const int b = (int)ctr[2];
  const long long j = (long long)ctr[4] - (long long)ctr[3];
  if (tid == 0){ rsel0 = 0x7f800000u; rsel1 = 0x7f800000u; minb2 = 0x7f800000u; }
  unsigned m = mB > 1024u ? 1024u : mB;
  for (unsigned i = tid; i < m; i += 256) vals[i] = bufB[i];
  __syncthreads();
  if (mB <= 1024u && m > 0){
    for (unsigned i = tid; i < m; i += 256){
      float v = vals[i]; unsigned rk = 0;
      for (unsigned x = 0; x < m; x++){
        float u = vals[x];
        rk += (u < v) || (u == v && x < i);
      }
      if ((long long)rk == j)     atomicMin(&rsel0, __builtin_bit_cast(unsigned, v));
      if ((long long)rk == j + 1) atomicMin(&rsel1, __builtin_bit_cast(unsigned, v));
    }
  }
  unsigned m2c = ctr[7]; unsigned m2 = m2c > 1024u ? 1024u : m2c;
  for (unsigned i = tid; i < m2; i += 256)
    atomicMin(&minb2, __builtin_bit_cast(unsigned, bufB2[i]));
  __syncthreads();
  if (tid == 0){
    float thr;
    if (mB > 1024u || m == 0 || j < 0 || j >= (long long)m){
      thr = lo + ((float)b + 0.5f) * binw;
    } else {
      float sR = __builtin_bit_cast(float, rsel0);
      float sR1;
      if (j + 1 < (long long)m) sR1 = __builtin_bit_cast(float, rsel1);
      else if (m2 > 0)          sR1 = __builtin_bit_cast(float, minb2);
      else                      sR1 = sR;
      if (!(sR1 < 3.0e38f)) sR1 = sR;
      thr = sR + QFRAC * (sR1 - sR);
    }
    sc[2] = thr;
  }
}

// ---- pass C: flash attention, static-max v_exp softmax, VALU-diet (R17-proven) ----
__global__ __launch_bounds__(256) void attn2_k(
    const u16* __restrict__ qhi, const u16* __restrict__ qlo,
    const u16* __restrict__ khi, const u16* __restrict__ klo,
    const u16* __restrict__ vt, const float* __restrict__ rowmax,
    u16* __restrict__ ohi, const float* __restrict__ sc)
{
  __shared__ u16 lKh[64*64];
  __shared__ u16 lKl[64*64];
  __shared__ u16 lV [64*64];
  __shared__ u16 lP [4*16*64];
  const int tid = threadIdx.x, lane = tid & 63, w = tid >> 6;
  const int g = lane >> 4, c = lane & 15;
  const int wid = (blockIdx.x & 7) * 128 + (blockIdx.x >> 3);   // XCD swizzle
  const int bh = wid >> 5, qt = wid & 31;
  const int qrow0 = qt*64 + w*16;
  const size_t base = (size_t)bh * (2048*64);
  const float thr = sc[2];

  f16x8 qfh[2], qfl[2];
  #pragma unroll
  for (int ks = 0; ks < 2; ks++){
    size_t off = base + (size_t)(qrow0 + c)*64 + ks*32 + g*8;
    qfh[ks] = *(const f16x8*)&qhi[off];
    qfl[ks] = *(const f16x8*)&qlo[off];
  }
  float mh[4];
  #pragma unroll
  for (int r = 0; r < 4; r++)
    mh[r] = rowmax[(size_t)bh * 2048 + qrow0 + g*4 + r];

  f16x8 vones;
  #pragma unroll
  for (int j = 0; j < 8; j++) vones[j] = (_Float16)1.0f;

  f32x4 O[4];
  f32x4 zacc = f32x4{0.f, 0.f, 0.f, 0.f};      // z via ones-MFMA (all 16 c-lanes hold row z)
  #pragma unroll
  for (int j = 0; j < 4; j++) O[j] = f32x4{0,0,0,0};

  for (int kt = 0; kt < 32; kt++){
    __syncthreads();
    #pragma unroll
    for (int i = 0; i < 2; i++){
      int ch = tid + i*256, row = ch >> 3, c8 = ch & 7;
      int di = swz(row, c8*8);
      size_t go = base + (size_t)(kt*64 + row)*64 + c8*8;
      *(uint4*)&lKh[di] = *(const uint4*)&khi[go];
      *(uint4*)&lKl[di] = *(const uint4*)&klo[go];
      size_t gv = base + (size_t)row * 2048 + kt*64 + c8*8;
      *(uint4*)&lV [di] = *(const uint4*)&vt[gv];
    }
    __syncthreads();

    f16x8 kfh[4][2], kfl[4][2];
    #pragma unroll
    for (int nf = 0; nf < 4; nf++)
      #pragma unroll
      for (int ks = 0; ks < 2; ks++){
        int off = swz(nf*16 + c, ks*32 + g*8);
        kfh[nf][ks] = *(const f16x8*)&lKh[off];
        kfl[nf][ks] = *(const f16x8*)&lKl[off];
      }

    f32x4 sa[4];
    __builtin_amdgcn_s_setprio(1);
    #pragma unroll
    for (int nf = 0; nf < 4; nf++){
      f32x4 a = f32x4{0,0,0,0};
      #pragma unroll
      for (int ks = 0; ks < 2; ks++){
        a = __builtin_amdgcn_mfma_f32_16x16x32_f16(qfh[ks], kfh[nf][ks], a, 0,0,0);
        a = __builtin_amdgcn_mfma_f32_16x16x32_f16(qfh[ks], kfl[nf][ks], a, 0,0,0);
        a = __builtin_amdgcn_mfma_f32_16x16x32_f16(qfl[ks], kfh[nf][ks], a, 0,0,0);
      }
      sa[nf] = a;                          // s2 space (q pre-scaled by 0.125/ln2)
    }
    __builtin_amdgcn_s_setprio(0);

    // mask: shared d = |s|-thr feeds keep test and (deferred) band test
    bool keep[4][4];
    float mind = 1e30f;
    #pragma unroll
    for (int nf = 0; nf < 4; nf++)
      #pragma unroll
      for (int r = 0; r < 4; r++){
        float d = __builtin_fabsf(sa[nf][r]) - thr;
        keep[nf][r] = (d >= 0.f);
        mind = fminf(mind, __builtin_fabsf(d));
      }
    if (__any(mind < EPS_REF)){            // rare: re-arbitrate boundary scores exactly
      #pragma unroll
      for (int nf = 0; nf < 4; nf++)
        #pragma unroll
        for (int r = 0; r < 4; r++){
          unsigned long long bal = __ballot(
              __builtin_fabsf(__builtin_fabsf(sa[nf][r]) - thr) < EPS_REF);
          while (bal){
            int L = (int)__ffsll((unsigned long long)bal) - 1; bal &= bal - 1;
            int qq = qrow0 + ((L >> 4) << 2) + r;
            int kk = kt*64 + nf*16 + (L & 15);
            double s = exact_score(qhi, qlo, khi, klo, base, qq, kk, lane);
            bool kp = ((float)fabs(s)) >= thr;
            if (lane == L) keep[nf][r] = kp;
          }
        }
    }

    #pragma unroll
    for (int nf = 0; nf < 4; nf++)
      #pragma unroll
      for (int r = 0; r < 4; r++){
        u16 ph = f2h(__builtin_amdgcn_exp2f(sa[nf][r] - mh[r]));
        ph = keep[nf][r] ? ph : (u16)0;
        int prow = g*4 + r;
        lP[(w << 10) + (prow << 6) + ((nf*16 + c) ^ ((prow & 7) << 3))] = ph;
      }

    // lP is wave-private (same-wave write->read; compiler orders LDS ops)
    f16x8 pa[2], vb[4][2];
    #pragma unroll
    for (int ks = 0; ks < 2; ks++)
      pa[ks] = *(const f16x8*)&lP[(w << 10) + (c << 6) + ((ks*32 + g*8) ^ ((c & 7) << 3))];
    #pragma unroll
    for (int nf = 0; nf < 4; nf++)
      #pragma unroll
      for (int ks = 0; ks < 2; ks++)
        vb[nf][ks] = *(const f16x8*)&lV[swz(nf*16 + c, ks*32 + g*8)];
    __builtin_amdgcn_s_setprio(1);
    #pragma unroll
    for (int ks = 0; ks < 2; ks++)
      zacc = __builtin_amdgcn_mfma_f32_16x16x32_f16(pa[ks], vones, zacc, 0,0,0);
    #pragma unroll
    for (int nf = 0; nf < 4; nf++)
      #pragma unroll
      for (int ks = 0; ks < 2; ks++)
        O[nf] = __builtin_amdgcn_mfma_f32_16x16x32_f16(pa[ks], vb[nf][ks], O[nf], 0,0,0);
    __builtin_amdgcn_s_setprio(0);
  }

  const int b = bh >> 4, h = bh & 15;
  #pragma unroll
  for (int r = 0; r < 4; r++){
    float z = zacc[r];                     // identical across the 16 c-lanes of this row
    float inv = (z > 0.f) ? (1.0f / z) : 0.f;
    int srow = qrow0 + g*4 + r;
    #pragma unroll
    for (int nf = 0; nf < 4; nf++){
      float v = O[nf][r] * inv;
      int d = nf*16 + c;
      size_t idx = ((size_t)(b*2048 + srow)) * 1024 + h*64 + d;
      ohi[idx] = f2h(v);
    }
  }
}

// ---------------- host ----------------
extern "C" void kernel_launch(void* const* d_in, const int* in_sizes, int n_in,
                              void* d_out, int out_size, void* d_ws, size_t ws_size,
                              hipStream_t stream)
{
  const float* x  = (const float*)d_in[0];
  const float* Wq = (const float*)d_in[1];
  const float* Wk = (const float*)d_in[2];
  const float* Wv = (const float*)d_in[3];
  const float* Wo = (const float*)d_in[4];

  char* p = (char*)d_ws;
  auto alloc = [&](size_t bytes) -> char* {
    char* r = p; p += (bytes + 255) & ~(size_t)255; return r;
  };
  const size_t NX = 4194304, NW = 1048576;
  u16* xh  = (u16*)alloc(NX*2); u16* xl  = (u16*)alloc(NX*2);
  u16* wqh = (u16*)alloc(NW*2); u16* wql = (u16*)alloc(NW*2);
  u16* wkh = (u16*)alloc(NW*2); u16* wkl = (u16*)alloc(NW*2);
  u16* wvh = (u16*)alloc(NW*2);
  u16* woh = (u16*)alloc(NW*2);
  u16* qh  = (u16*)alloc(NX*2); u16* ql  = (u16*)alloc(NX*2);
  u16* kh  = (u16*)alloc(NX*2); u16* kl  = (u16*)alloc(NX*2);
  u16* vth = (u16*)alloc(NX*2);
  u16* oh  = (u16*)alloc(NX*2); u16* ol  = (u16*)alloc(NX*2);
  float*    rowmax = (float*)alloc(65536*4);    // [B*H][S]
  unsigned* histc = (unsigned*)alloc(8192*4);
  unsigned* hist2 = (unsigned*)alloc(8192*4);
  unsigned* ctr   = (unsigned*)alloc(256);
  float*    sc    = (float*)alloc(256);
  float*    bufB  = (float*)alloc(1024*4);
  float*    bufB2 = (float*)alloc(1024*4);
  if ((size_t)(p - (char*)d_ws) > ws_size) return;
  unsigned* candidx = (unsigned*)oh;            // alias: dead before oh written
  float*    candval = (float*)ol;               // alias: ol otherwise unused now

  hipMemsetAsync(histc, 0, 8192*4*2 + 256 + 256, stream);   // histc+hist2+ctr+sc

  dim3 gb(256);
  split_all<<<dim3(2048), gb, 0, stream>>>(x, Wq, Wk, Wv, Wo,
      xh, xl, wqh, wql, wkh, wkl, wvh, woh);

  gemm_projQKV<<<dim3(48, 32), gb, 0, stream>>>(xh, xl, wqh, wql, wkh, wkl, wvh,
                                                qh, ql, kh, kl, vth);

  hist_sub   <<<dim3(256),  gb, 0, stream>>>(qh, kh, histc);
  scan_window<<<dim3(1),    gb, 0, stream>>>(histc, sc);
  collect_k  <<<dim3(1024), gb, 0, stream>>>(qh, kh, sc, candidx, ctr, rowmax);
  refine_k   <<<dim3(2048), gb, 0, stream>>>(qh, ql, kh, kl, candidx, ctr, candval, sc, hist2);
  scan_b     <<<dim3(1),    gb, 0, stream>>>(hist2, ctr);
  extract_k  <<<dim3(64),   gb, 0, stream>>>(candval, ctr, sc, bufB, bufB2);
  final_k    <<<dim3(1),    gb, 0, stream>>>(bufB, bufB2, ctr, sc);
  attn2_k    <<<dim3(1024), gb, 0, stream>>>(qh, ql, kh, kl, vth, rowmax, oh, sc);

  gemm_out<<<dim3(16, 64), gb, 0, stream>>>(oh, woh, (float*)d_out);
}

// Round 23
// 415.180 us; speedup vs baseline: 1.0458x; 1.0072x over previous
//
#include <hip/hip_runtime.h>
#include <stdint.h>

typedef float f32x4 __attribute__((ext_vector_type(4)));
typedef _Float16 f16x8 __attribute__((ext_vector_type(8)));
typedef unsigned short u16;

#define DEVI static __device__ __forceinline__

DEVI u16 f2h(float f){ _Float16 h = (_Float16)f; return __builtin_bit_cast(u16, h); }
DEVI float h2f(u16 b){ return (float)__builtin_bit_cast(_Float16, b); }
// XOR-swizzled u16 index into a [rows][64] u16 LDS tile (row pitch 128B) — proven 0-conflict (R5).
DEVI int swz(int row, int col){ return (row << 6) + (col ^ ((row & 7) << 3)); }

static constexpr unsigned RANK = 120795954u;   // floor(0.9 * (2*16*2048*2048 - 1))
static constexpr float QFRAC = 0.3f;           // frac part of 0.9*(n-1)
static constexpr float CW = 1.0f / 512.0f;     // coarse bin width over [0,16) (s2 space)
static constexpr unsigned CAP = 1u << 20;      // candidate slots
static constexpr float EPS_REF = 6e-6f;        // boundary band (s2 space)
static constexpr float QSCALE = 0.18033688011112042f;  // 0.125/ln2 folded into stored q

// ---------------- fused split: all 5 inputs -> f16 hi (+ lo where needed) ----------
__global__ __launch_bounds__(256) void split_all(
    const float* __restrict__ x,  const float* __restrict__ wq,
    const float* __restrict__ wk, const float* __restrict__ wv,
    const float* __restrict__ wo,
    u16* __restrict__ xh,  u16* __restrict__ xl,
    u16* __restrict__ wqh, u16* __restrict__ wql,
    u16* __restrict__ wkh, u16* __restrict__ wkl,
    u16* __restrict__ wvh, u16* __restrict__ woh)
{
  const int stride = gridDim.x * 256;
  for (int i = blockIdx.x * 256 + threadIdx.x; i < 2097152; i += stride){
    const float* src; u16* hi; u16* lo; int off;
    if (i < 1048576)      { src = x;  hi = xh;  lo = xl;  off = i; }
    else if (i < 1310720) { src = wq; hi = wqh; lo = wql; off = i - 1048576; }
    else if (i < 1572864) { src = wk; hi = wkh; lo = wkl; off = i - 1310720; }
    else if (i < 1835008) { src = wv; hi = wvh; lo = nullptr; off = i - 1572864; }
    else                  { src = wo; hi = woh; lo = nullptr; off = i - 1835008; }
    float4 v = ((const float4*)src)[off];
    u16 h0 = f2h(v.x), h1 = f2h(v.y), h2 = f2h(v.z), h3 = f2h(v.w);
    ((ushort4*)hi)[off] = make_ushort4(h0, h1, h2, h3);
    if (lo)
      ((ushort4*)lo)[off] = make_ushort4(f2h(v.x - h2f(h0)), f2h(v.y - h2f(h1)),
                                         f2h(v.z - h2f(h2)), f2h(v.w - h2f(h3)));
  }
}

// ---- fused Q+K+V projection GEMM, single launch (48x32 grid, 2-wave packing) ------
__global__ __launch_bounds__(256) void gemm_projQKV(
    const u16* __restrict__ Ah, const u16* __restrict__ Al,
    const u16* __restrict__ wqh, const u16* __restrict__ wql,
    const u16* __restrict__ wkh, const u16* __restrict__ wkl,
    const u16* __restrict__ wvh,
    u16* __restrict__ qh, u16* __restrict__ ql,
    u16* __restrict__ kh, u16* __restrict__ kl, u16* __restrict__ vth)
{
  __shared__ u16 lAh[128*64], lAl[128*64];
  __shared__ u16 lBh[64*64],  lBl[64*64];
  const int tid = threadIdx.x;
  const int which = blockIdx.x >> 4;
  const int m0 = blockIdx.y * 128, n0 = (blockIdx.x & 15) * 64;
  const int lane = tid & 63, w = tid >> 6;
  const int wm = w >> 1, wn = w & 1;
  const int g = lane >> 4, c = lane & 15;

  if (which == 2){
    // ---------------- V body: 1-term hi-only, transposed store ----------------
    f32x4 acc[4][2];
    #pragma unroll
    for (int i = 0; i < 4; i++)
      #pragma unroll
      for (int j = 0; j < 2; j++) acc[i][j] = f32x4{0,0,0,0};

    for (int k0 = 0; k0 < 1024; k0 += 64){
      __syncthreads();
      #pragma unroll
      for (int i = 0; i < 4; i++){
        int ch = tid + i*256, row = ch >> 3, c8 = ch & 7;
        *(uint4*)&lAh[swz(row, c8*8)] = *(const uint4*)&Ah[(size_t)(m0 + row) * 1024 + k0 + c8*8];
      }
      #pragma unroll
      for (int i = 0; i < 2; i++){
        int ch = tid + i*256, row = ch >> 3, c8 = ch & 7;
        *(uint4*)&lBh[swz(row, c8*8)] = *(const uint4*)&wvh[(size_t)(n0 + row) * 1024 + k0 + c8*8];
      }
      __syncthreads();
      f16x8 ah[4][2], bh[2][2];
      #pragma unroll
      for (int mf = 0; mf < 4; mf++)
        #pragma unroll
        for (int ks = 0; ks < 2; ks++)
          ah[mf][ks] = *(const f16x8*)&lAh[swz(wm*64 + mf*16 + c, ks*32 + g*8)];
      #pragma unroll
      for (int nf = 0; nf < 2; nf++)
        #pragma unroll
        for (int ks = 0; ks < 2; ks++)
          bh[nf][ks] = *(const f16x8*)&lBh[swz(wn*32 + nf*16 + c, ks*32 + g*8)];
      __builtin_amdgcn_s_setprio(1);
      #pragma unroll
      for (int mf = 0; mf < 4; mf++)
        #pragma unroll
        for (int nf = 0; nf < 2; nf++)
          #pragma unroll
          for (int ks = 0; ks < 2; ks++)
            acc[mf][nf] = __builtin_amdgcn_mfma_f32_16x16x32_f16(ah[mf][ks], bh[nf][ks], acc[mf][nf], 0,0,0);
      __builtin_amdgcn_s_setprio(0);
    }
    #pragma unroll
    for (int mf = 0; mf < 4; mf++)
      #pragma unroll
      for (int nf = 0; nf < 2; nf++)
        #pragma unroll
        for (int r = 0; r < 4; r++){
          int m = m0 + wm*64 + mf*16 + g*4 + r;
          int n = n0 + wn*32 + nf*16 + c;
          int b = m >> 11, s = m & 2047, h = n >> 6, d = n & 63;
          size_t idx = (((size_t)(b*16 + h)) * 64 + d) * 2048 + s;
          vth[idx] = f2h(acc[mf][nf][r]);
        }
    return;
  }

  // ---------------- Q/K body: 3-term, branch-free inner loops ----------------
  const u16* __restrict__ Bh = which == 0 ? wqh : wkh;
  const u16* __restrict__ Bl = which == 0 ? wql : wkl;
  f32x4 acc[4][2];
  #pragma unroll
  for (int i = 0; i < 4; i++)
    #pragma unroll
    for (int j = 0; j < 2; j++) acc[i][j] = f32x4{0,0,0,0};

  for (int k0 = 0; k0 < 1024; k0 += 64){
    __syncthreads();
    #pragma unroll
    for (int i = 0; i < 4; i++){                     // A: 128 rows x 64 u16
      int ch = tid + i*256, row = ch >> 3, c8 = ch & 7;
      int di = swz(row, c8*8);
      size_t ga = (size_t)(m0 + row) * 1024 + k0 + c8*8;
      *(uint4*)&lAh[di] = *(const uint4*)&Ah[ga];
      *(uint4*)&lAl[di] = *(const uint4*)&Al[ga];
    }
    #pragma unroll
    for (int i = 0; i < 2; i++){                     // B: 64 rows x 64 u16
      int ch = tid + i*256, row = ch >> 3, c8 = ch & 7;
      int di = swz(row, c8*8);
      size_t gb = (size_t)(n0 + row) * 1024 + k0 + c8*8;
      *(uint4*)&lBh[di] = *(const uint4*)&Bh[gb];
      *(uint4*)&lBl[di] = *(const uint4*)&Bl[gb];
    }
    __syncthreads();
    f16x8 ah[4][2], al[4][2], bh[2][2], bl[2][2];
    #pragma unroll
    for (int mf = 0; mf < 4; mf++)
      #pragma unroll
      for (int ks = 0; ks < 2; ks++){
        int off = swz(wm*64 + mf*16 + c, ks*32 + g*8);
        ah[mf][ks] = *(const f16x8*)&lAh[off];
        al[mf][ks] = *(const f16x8*)&lAl[off];
      }
    #pragma unroll
    for (int nf = 0; nf < 2; nf++)
      #pragma unroll
      for (int ks = 0; ks < 2; ks++){
        int off = swz(wn*32 + nf*16 + c, ks*32 + g*8);
        bh[nf][ks] = *(const f16x8*)&lBh[off];
        bl[nf][ks] = *(const f16x8*)&lBl[off];
      }
    __builtin_amdgcn_s_setprio(1);
    #pragma unroll
    for (int mf = 0; mf < 4; mf++)
      #pragma unroll
      for (int nf = 0; nf < 2; nf++)
        #pragma unroll
        for (int ks = 0; ks < 2; ks++){
          acc[mf][nf] = __builtin_amdgcn_mfma_f32_16x16x32_f16(ah[mf][ks], bh[nf][ks], acc[mf][nf], 0,0,0);
          acc[mf][nf] = __builtin_amdgcn_mfma_f32_16x16x32_f16(ah[mf][ks], bl[nf][ks], acc[mf][nf], 0,0,0);
          acc[mf][nf] = __builtin_amdgcn_mfma_f32_16x16x32_f16(al[mf][ks], bh[nf][ks], acc[mf][nf], 0,0,0);
        }
    __builtin_amdgcn_s_setprio(0);
  }
  #pragma unroll
  for (int mf = 0; mf < 4; mf++)
    #pragma unroll
    for (int nf = 0; nf < 2; nf++)
      #pragma unroll
      for (int r = 0; r < 4; r++){
        int m = m0 + wm*64 + mf*16 + g*4 + r;
        int n = n0 + wn*32 + nf*16 + c;
        float v = acc[mf][nf][r];
        int b = m >> 11, s = m & 2047, h = n >> 6, d = n & 63;
        size_t idx = (((size_t)(b*16 + h)) * 2048 + s) * 64 + d;
        if (which == 0){
          v *= QSCALE;                          // fold 0.125/ln2 into stored q
          u16 hv = f2h(v);
          qh[idx] = hv; ql[idx] = f2h(v - h2f(hv));
        } else {
          u16 hv = f2h(v);
          kh[idx] = hv; kl[idx] = f2h(v - h2f(hv));
        }
      }
}

// ---- output projection GEMM: hi-only 1-term, 64x64 tiles (1024 blocks, 4/CU) ------
__global__ __launch_bounds__(256) void gemm_out(
    const u16* __restrict__ Ahi, const u16* __restrict__ Bhi,
    float* __restrict__ out)
{
  __shared__ u16 lAh[64*64];
  __shared__ u16 lBh[64*64];
  const int tid = threadIdx.x;
  const int m0 = blockIdx.y * 64, n0 = blockIdx.x * 64;
  const int lane = tid & 63, w = tid >> 6;
  const int wm = w >> 1, wn = w & 1;
  const int g = lane >> 4, c = lane & 15;
  f32x4 acc[2][2];
  #pragma unroll
  for (int i = 0; i < 2; i++)
    #pragma unroll
    for (int j = 0; j < 2; j++) acc[i][j] = f32x4{0,0,0,0};

  for (int k0 = 0; k0 < 1024; k0 += 64){
    __syncthreads();
    #pragma unroll
    for (int i = 0; i < 2; i++){
      int ch = tid + i*256, row = ch >> 3, c8 = ch & 7;
      *(uint4*)&lAh[swz(row, c8*8)] = *(const uint4*)&Ahi[(size_t)(m0 + row) * 1024 + k0 + c8*8];
    }
    #pragma unroll
    for (int i = 0; i < 2; i++){
      int ch = tid + i*256, row = ch >> 3, c8 = ch & 7;
      *(uint4*)&lBh[swz(row, c8*8)] = *(const uint4*)&Bhi[(size_t)(n0 + row) * 1024 + k0 + c8*8];
    }
    __syncthreads();
    f16x8 ah[2][2], bh[2][2];
    #pragma unroll
    for (int mf = 0; mf < 2; mf++)
      #pragma unroll
      for (int ks = 0; ks < 2; ks++)
        ah[mf][ks] = *(const f16x8*)&lAh[swz(wm*32 + mf*16 + c, ks*32 + g*8)];
    #pragma unroll
    for (int nf = 0; nf < 2; nf++)
      #pragma unroll
      for (int ks = 0; ks < 2; ks++)
        bh[nf][ks] = *(const f16x8*)&lBh[swz(wn*32 + nf*16 + c, ks*32 + g*8)];
    __builtin_amdgcn_s_setprio(1);
    #pragma unroll
    for (int mf = 0; mf < 2; mf++)
      #pragma unroll
      for (int nf = 0; nf < 2; nf++)
        #pragma unroll
        for (int ks = 0; ks < 2; ks++)
          acc[mf][nf] = __builtin_amdgcn_mfma_f32_16x16x32_f16(ah[mf][ks], bh[nf][ks], acc[mf][nf], 0,0,0);
    __builtin_amdgcn_s_setprio(0);
  }
  #pragma unroll
  for (int mf = 0; mf < 2; mf++)
    #pragma unroll
    for (int nf = 0; nf < 2; nf++)
      #pragma unroll
      for (int r = 0; r < 4; r++){
        int m = m0 + wm*32 + mf*16 + g*4 + r;
        int n = n0 + wn*32 + nf*16 + c;
        out[(size_t)m * 1024 + n] = acc[mf][nf][r];
      }
}

// ------- exact f64 score (s2 space) of stored q*,k — bit-identical everywhere -------
DEVI double exact_score(const u16* __restrict__ qh, const u16* __restrict__ ql,
                        const u16* __restrict__ kh, const u16* __restrict__ kl,
                        size_t base, int q, int k, int lane){
  size_t qo = base + (size_t)q * 64 + lane;
  size_t ko = base + (size_t)k * 64 + lane;
  double qd = (double)h2f(qh[qo]) + (double)h2f(ql[qo]);
  double kd = (double)h2f(kh[ko]) + (double)h2f(kl[ko]);
  double p = qd * kd;
  #pragma unroll
  for (int d = 1; d < 64; d <<= 1) p += __shfl_xor(p, d, 64);
  return p;
}

// ------ pass A: subsampled coarse histogram (f16-hi QK, s2 space), kt-split x4 ------
__global__ __launch_bounds__(256) void hist_sub(const u16* __restrict__ qh,
    const u16* __restrict__ kh, unsigned* __restrict__ ghist){
  __shared__ u16 lK[64*64];
  __shared__ unsigned lh[8192];
  const int tid = threadIdx.x, lane = tid & 63, w = tid >> 6;
  const int g = lane >> 4, c = lane & 15;
  const int bh = blockIdx.x >> 3, rem = blockIdx.x & 7;
  const int qt = rem & 1, quarter = rem >> 1;
  const int qrow0 = qt*64 + w*16;
  const size_t base = (size_t)bh * (2048*64);
  #pragma unroll
  for (int i = 0; i < 32; i++) lh[tid + i*256] = 0u;
  f16x8 qf[2];
  #pragma unroll
  for (int ks = 0; ks < 2; ks++)
    qf[ks] = *(const f16x8*)&qh[base + (size_t)(qrow0 + c)*64 + ks*32 + g*8];

  const int kt0 = quarter * 8;
  for (int kt = kt0; kt < kt0 + 8; kt++){
    __syncthreads();
    #pragma unroll
    for (int i = 0; i < 2; i++){
      int ch = tid + i*256, row = ch >> 3, c8 = ch & 7;
      *(uint4*)&lK[swz(row, c8*8)] = *(const uint4*)&kh[base + (size_t)(kt*64 + row)*64 + c8*8];
    }
    __syncthreads();
    #pragma unroll
    for (int nf = 0; nf < 4; nf++){
      f16x8 k0 = *(const f16x8*)&lK[swz(nf*16 + c, g*8)];
      f16x8 k1 = *(const f16x8*)&lK[swz(nf*16 + c, 32 + g*8)];
      f32x4 a = f32x4{0,0,0,0};
      a = __builtin_amdgcn_mfma_f32_16x16x32_f16(qf[0], k0, a, 0,0,0);
      a = __builtin_amdgcn_mfma_f32_16x16x32_f16(qf[1], k1, a, 0,0,0);
      #pragma unroll
      for (int r = 0; r < 4; r++){
        float v = __builtin_fabsf(a[r]);
        int idx = (int)fminf(v * 512.f, 8191.f);
        atomicAdd(&lh[idx], 1u);
      }
    }
  }
  __syncthreads();
  #pragma unroll
  for (int i = 0; i < 32; i++){
    unsigned cnt = lh[tid + i*256];
    if (cnt) atomicAdd(&ghist[tid + i*256], cnt);
  }
}

// ---------------- window scan (1 block) ----------------
__global__ __launch_bounds__(256) void scan_window(const unsigned* __restrict__ ghist,
    float* __restrict__ sc){
  __shared__ unsigned bins[8192];
  __shared__ unsigned part[256];
  int tid = threadIdx.x;
  unsigned s = 0;
  for (int i = 0; i < 32; i++){ unsigned v = ghist[tid*32 + i]; bins[tid*32 + i] = v; s += v; }
  part[tid] = s;
  __syncthreads();
  if (tid == 0){
    unsigned long long total = 0;
    for (int i = 0; i < 256; i++) total += part[i];
    unsigned long long target = (unsigned long long)(0.9 * (double)total);
    unsigned long long cum = 0; int seg = 0;
    for (; seg < 255; seg++){ if (cum + part[seg] > target) break; cum += part[seg]; }
    int b = seg * 32;
    while (b < 8191 && cum + bins[b] <= target){ cum += bins[b]; b++; }
    int blo = b - 4; if (blo < 0) blo = 0;
    int bhi = b + 5; if (bhi > 8191) bhi = 8191;
    sc[0] = (float)blo * CW;
    sc[1] = (float)bhi * CW;
  }
}

// ---- pass B (R5 structure + 2-kt staging): LDS-staged K, block buffer, rowmax ----
__global__ __launch_bounds__(256) void collect_k(const u16* __restrict__ qh,
    const u16* __restrict__ kh, const float* __restrict__ sc,
    unsigned* __restrict__ candidx, unsigned* __restrict__ ctr,
    float* __restrict__ rowmax){
  __shared__ u16 lK[2][64*64];                  // 16 KB: two K-tiles per barrier pair
  __shared__ unsigned lbuf[4096];
  __shared__ unsigned lcnt, gbase;
  const int tid = threadIdx.x, lane = tid & 63, w = tid >> 6;
  const int g = lane >> 4, c = lane & 15;
  const int wid = (blockIdx.x & 7) * 128 + (blockIdx.x >> 3);   // XCD swizzle (1024)
  const int bh = wid >> 5, qt = wid & 31;
  const int qrow0 = qt*64 + w*16;
  const size_t base = (size_t)bh * (2048*64);
  const float lo = sc[0], hi = sc[1];
  if (tid == 0) lcnt = 0u;
  f16x8 qf[2];
  #pragma unroll
  for (int ks = 0; ks < 2; ks++)
    qf[ks] = *(const f16x8*)&qh[base + (size_t)(qrow0 + c)*64 + ks*32 + g*8];
  unsigned cnt = 0;
  float rm[4] = {-1e30f, -1e30f, -1e30f, -1e30f};

  for (int kt2 = 0; kt2 < 16; kt2++){
    __syncthreads();
    #pragma unroll
    for (int t = 0; t < 2; t++)
      #pragma unroll
      for (int i = 0; i < 2; i++){
        int ch = tid + i*256, row = ch >> 3, c8 = ch & 7;
        *(uint4*)&lK[t][swz(row, c8*8)] =
            *(const uint4*)&kh[base + (size_t)((kt2*2 + t)*64 + row)*64 + c8*8];
      }
    __syncthreads();
    #pragma unroll
    for (int t = 0; t < 2; t++){
      const int kt = kt2*2 + t;
      #pragma unroll
      for (int nf = 0; nf < 4; nf++){
        f16x8 k0 = *(const f16x8*)&lK[t][swz(nf*16 + c, g*8)];
        f16x8 k1 = *(const f16x8*)&lK[t][swz(nf*16 + c, 32 + g*8)];
        f32x4 a = f32x4{0,0,0,0};
        a = __builtin_amdgcn_mfma_f32_16x16x32_f16(qf[0], k0, a, 0,0,0);
        a = __builtin_amdgcn_mfma_f32_16x16x32_f16(qf[1], k1, a, 0,0,0);
        #pragma unroll
        for (int r = 0; r < 4; r++){
          float s = a[r];
          float v = __builtin_fabsf(s);
          rm[r] = fmaxf(rm[r], s);
          cnt += (v < lo) ? 1u : 0u;
          if (v >= lo && v < hi){
            int qq = qrow0 + g*4 + r;
            int kk = kt*64 + nf*16 + c;
            unsigned pk = ((unsigned)bh << 22) | ((unsigned)qq << 11) | (unsigned)kk;
            unsigned p = atomicAdd(&lcnt, 1u);
            if (p < 4096u) lbuf[p] = pk;
            else { unsigned gp = atomicAdd(&ctr[0], 1u); if (gp < CAP) candidx[gp] = pk; }
          }
        }
      }
    }
    __syncthreads();
    if (lcnt >= 2048u){
      unsigned cflush = lcnt; if (cflush > 4096u) cflush = 4096u;
      if (tid == 0) gbase = atomicAdd(&ctr[0], cflush);
      __syncthreads();
      for (unsigned i = tid; i < cflush; i += 256){
        unsigned p = gbase + i; if (p < CAP) candidx[p] = lbuf[i];
      }
      __syncthreads();
      if (tid == 0) lcnt = 0u;
    }
  }
  __syncthreads();
  { unsigned cflush = lcnt; if (cflush > 4096u) cflush = 4096u;
    if (tid == 0) gbase = atomicAdd(&ctr[0], cflush);
    __syncthreads();
    for (unsigned i = tid; i < cflush; i += 256){
      unsigned p = gbase + i; if (p < CAP) candidx[p] = lbuf[i];
    }
  }
  #pragma unroll
  for (int r = 0; r < 4; r++){
    float m = rm[r];
    m = fmaxf(m, __shfl_xor(m, 1, 64));
    m = fmaxf(m, __shfl_xor(m, 2, 64));
    m = fmaxf(m, __shfl_xor(m, 4, 64));
    m = fmaxf(m, __shfl_xor(m, 8, 64));
    if (c == 0) rowmax[(size_t)bh * 2048 + qrow0 + g*4 + r] = m;
  }
  #pragma unroll
  for (int d = 1; d < 64; d <<= 1) cnt += __shfl_xor(cnt, d, 64);
  if (lane == 0) atomicAdd(&ctr[1], cnt);
}

// ---- refine: exact f64 score per candidate (one per wave) + fused histogram ----
__global__ __launch_bounds__(256) void refine_k(const u16* __restrict__ qh,
    const u16* __restrict__ ql, const u16* __restrict__ kh, const u16* __restrict__ kl,
    const unsigned* __restrict__ candidx, const unsigned* __restrict__ ctr,
    float* __restrict__ candval, const float* __restrict__ sc,
    unsigned* __restrict__ h2){
  const int lane = threadIdx.x & 63;
  const unsigned gw = blockIdx.x * 4 + (threadIdx.x >> 6);
  const unsigned nw = gridDim.x * 4;
  unsigned n = ctr[0]; if (n > CAP) n = CAP;
  const float lo = sc[0], hi = sc[1];
  const float inv = 8192.0f / (hi - lo);
  for (unsigned i = gw; i < n; i += nw){
    unsigned pk = candidx[i];
    int bh = pk >> 22, q = (pk >> 11) & 2047, k = pk & 2047;
    double s = exact_score(qh, ql, kh, kl, (size_t)bh * (2048*64), q, k, lane);
    if (lane == 0){
      float av = (float)fabs(s);
      candval[i] = av;
      int idx = (int)((av - lo) * inv);
      idx = idx < 0 ? 0 : (idx > 8191 ? 8191 : idx);
      atomicAdd(&h2[idx], 1u);
    }
  }
}

// ---------------- find target bin b, base rank, next non-empty bin (1 block) ----
__global__ __launch_bounds__(256) void scan_b(const unsigned* __restrict__ h2,
    unsigned* __restrict__ ctr){
  __shared__ unsigned bins[8192];
  __shared__ unsigned part[256];
  const int tid = threadIdx.x;
  unsigned s = 0;
  for (int i = 0; i < 32; i++){ unsigned v = h2[tid*32 + i]; bins[tid*32 + i] = v; s += v; }
  part[tid] = s;
  __syncthreads();
  if (tid == 0){
    unsigned n = ctr[0]; if (n > CAP) n = CAP;
    long long r2 = (long long)RANK - (long long)ctr[1];
    if (r2 < 0) r2 = 0;
    if (n > 0 && r2 >= (long long)n) r2 = (long long)n - 1;
    unsigned long long cum = 0; int seg = 0;
    for (; seg < 255; seg++){ if (cum + part[seg] > (unsigned long long)r2) break; cum += part[seg]; }
    int b = seg * 32;
    while (b < 8191 && cum + bins[b] <= (unsigned long long)r2){ cum += bins[b]; b++; }
    int b2 = -1;
    for (int x = b + 1; x < 8192; x++){ if (bins[x]){ b2 = x; break; } }
    ctr[2] = (unsigned)b;
    ctr[3] = (unsigned)cum;
    ctr[4] = (unsigned)r2;
    ctr[5] = (unsigned)(b2 + 1);          // 0 = none
  }
}

// ---------------- extract bin-b and bin-b2 members ----------------
__global__ __launch_bounds__(256) void extract_k(const float* __restrict__ cand,
    unsigned* __restrict__ ctr, const float* __restrict__ sc,
    float* __restrict__ bufB, float* __restrict__ bufB2){
  const int tid = threadIdx.x;
  unsigned n = ctr[0]; if (n > CAP) n = CAP;
  const float lo = sc[0], hi = sc[1];
  const float inv = 8192.0f / (hi - lo);
  const int b = (int)ctr[2];
  const int b2 = (int)ctr[5] - 1;
  const unsigned stride = gridDim.x * 256;
  for (unsigned i = blockIdx.x * 256 + tid; i < n; i += stride){
    float v = cand[i];
    int idx = (int)((v - lo) * inv);
    idx = idx < 0 ? 0 : (idx > 8191 ? 8191 : idx);
    if (idx == b){
      unsigned p = atomicAdd(&ctr[6], 1u);
      if (p < 1024u) bufB[p] = v;
    } else if (idx == b2){
      unsigned p = atomicAdd(&ctr[7], 1u);
      if (p < 1024u) bufB2[p] = v;
    }
  }
}

// ---------------- final: parallel rank-select j-th / (j+1)-th smallest ----------
__global__ __launch_bounds__(256) void final_k(const float* __restrict__ bufB,
    const float* __restrict__ bufB2, const unsigned* __restrict__ ctr,
    float* __restrict__ sc){
  __shared__ float vals[1024];
  __shared__ unsigned rsel0, rsel1, minb2;
  const int tid = threadIdx.x;
  const unsigned mB = ctr[6];
  const float lo = sc[0], hi = sc[1];
  const float binw = (hi - lo) * (1.0f / 8192.0f);
  const int b = (int)ctr[2];
  const long long j = (long long)ctr[4] - (long long)ctr[3];
  if (tid == 0){ rsel0 = 0x7f800000u; rsel1 = 0x7f800000u; minb2 = 0x7f800000u; }
  unsigned m = mB > 1024u ? 1024u : mB;
  for (unsigned i = tid; i < m; i += 256) vals[i] = bufB[i];
  __syncthreads();
  if (mB <= 1024u && m > 0){
    for (unsigned i = tid; i < m; i += 256){
      float v = vals[i]; unsigned rk = 0;
      for (unsigned x = 0; x < m; x++){
        float u = vals[x];
        rk += (u < v) || (u == v && x < i);
      }
      if ((long long)rk == j)     atomicMin(&rsel0, __builtin_bit_cast(unsigned, v));
      if ((long long)rk == j + 1) atomicMin(&rsel1, __builtin_bit_cast(unsigned, v));
    }
  }
  unsigned m2c = ctr[7]; unsigned m2 = m2c > 1024u ? 1024u : m2c;
  for (unsigned i = tid; i < m2; i += 256)
    atomicMin(&minb2, __builtin_bit_cast(unsigned, bufB2[i]));
  __syncthreads();
  if (tid == 0){
    float thr;
    if (mB > 1024u || m == 0 || j < 0 || j >= (long long)m){
      thr = lo + ((float)b + 0.5f) * binw;
    } else {
      float sR = __builtin_bit_cast(float, rsel0);
      float sR1;
      if (j + 1 < (long long)m) sR1 = __builtin_bit_cast(float, rsel1);
      else if (m2 > 0)          sR1 = __builtin_bit_cast(float, minb2);
      else                      sR1 = sR;
      if (!(sR1 < 3.0e38f)) sR1 = sR;
      thr = sR + QFRAC * (sR1 - sR);
    }
    sc[2] = thr;
  }
}

// ---- pass C: flash attention, static-max v_exp softmax, VALU-diet (R17-proven) ----
__global__ __launch_bounds__(256) void attn2_k(
    const u16* __restrict__ qhi, const u16* __restrict__ qlo,
    const u16* __restrict__ khi, const u16* __restrict__ klo,
    const u16* __restrict__ vt, const float* __restrict__ rowmax,
    u16* __restrict__ ohi, const float* __restrict__ sc)
{
  __shared__ u16 lKh[64*64];
  __shared__ u16 lKl[64*64];
  __shared__ u16 lV [64*64];
  __shared__ u16 lP [4*16*64];
  const int tid = threadIdx.x, lane = tid & 63, w = tid >> 6;
  const int g = lane >> 4, c = lane & 15;
  const int wid = (blockIdx.x & 7) * 128 + (blockIdx.x >> 3);   // XCD swizzle
  const int bh = wid >> 5, qt = wid & 31;
  const int qrow0 = qt*64 + w*16;
  const size_t base = (size_t)bh * (2048*64);
  const float thr = sc[2];

  f16x8 qfh[2], qfl[2];
  #pragma unroll
  for (int ks = 0; ks < 2; ks++){
    size_t off = base + (size_t)(qrow0 + c)*64 + ks*32 + g*8;
    qfh[ks] = *(const f16x8*)&qhi[off];
    qfl[ks] = *(const f16x8*)&qlo[off];
  }
  float mh[4];
  #pragma unroll
  for (int r = 0; r < 4; r++)
    mh[r] = rowmax[(size_t)bh * 2048 + qrow0 + g*4 + r];

  f16x8 vones;
  #pragma unroll
  for (int j = 0; j < 8; j++) vones[j] = (_Float16)1.0f;

  f32x4 O[4];
  f32x4 zacc = f32x4{0.f, 0.f, 0.f, 0.f};      // z via ones-MFMA (all 16 c-lanes hold row z)
  #pragma unroll
  for (int j = 0; j < 4; j++) O[j] = f32x4{0,0,0,0};

  for (int kt = 0; kt < 32; kt++){
    __syncthreads();
    #pragma unroll
    for (int i = 0; i < 2; i++){
      int ch = tid + i*256, row = ch >> 3, c8 = ch & 7;
      int di = swz(row, c8*8);
      size_t go = base + (size_t)(kt*64 + row)*64 + c8*8;
      *(uint4*)&lKh[di] = *(const uint4*)&khi[go];
      *(uint4*)&lKl[di] = *(const uint4*)&klo[go];
      size_t gv = base + (size_t)row * 2048 + kt*64 + c8*8;
      *(uint4*)&lV [di] = *(const uint4*)&vt[gv];
    }
    __syncthreads();

    f16x8 kfh[4][2], kfl[4][2];
    #pragma unroll
    for (int nf = 0; nf < 4; nf++)
      #pragma unroll
      for (int ks = 0; ks < 2; ks++){
        int off = swz(nf*16 + c, ks*32 + g*8);
        kfh[nf][ks] = *(const f16x8*)&lKh[off];
        kfl[nf][ks] = *(const f16x8*)&lKl[off];
      }

    f32x4 sa[4];
    __builtin_amdgcn_s_setprio(1);
    #pragma unroll
    for (int nf = 0; nf < 4; nf++){
      f32x4 a = f32x4{0,0,0,0};
      #pragma unroll
      for (int ks = 0; ks < 2; ks++){
        a = __builtin_amdgcn_mfma_f32_16x16x32_f16(qfh[ks], kfh[nf][ks], a, 0,0,0);
        a = __builtin_amdgcn_mfma_f32_16x16x32_f16(qfh[ks], kfl[nf][ks], a, 0,0,0);
        a = __builtin_amdgcn_mfma_f32_16x16x32_f16(qfl[ks], kfh[nf][ks], a, 0,0,0);
      }
      sa[nf] = a;                          // s2 space (q pre-scaled by 0.125/ln2)
    }
    __builtin_amdgcn_s_setprio(0);

    // mask: shared d = |s|-thr feeds keep test and (deferred) band test
    bool keep[4][4];
    float mind = 1e30f;
    #pragma unroll
    for (int nf = 0; nf < 4; nf++)
      #pragma unroll
      for (int r = 0; r < 4; r++){
        float d = __builtin_fabsf(sa[nf][r]) - thr;
        keep[nf][r] = (d >= 0.f);
        mind = fminf(mind, __builtin_fabsf(d));
      }
    if (__any(mind < EPS_REF)){            // rare: re-arbitrate boundary scores exactly
      #pragma unroll
      for (int nf = 0; nf < 4; nf++)
        #pragma unroll
        for (int r = 0; r < 4; r++){
          unsigned long long bal = __ballot(
              __builtin_fabsf(__builtin_fabsf(sa[nf][r]) - thr) < EPS_REF);
          while (bal){
            int L = (int)__ffsll((unsigned long long)bal) - 1; bal &= bal - 1;
            int qq = qrow0 + ((L >> 4) << 2) + r;
            int kk = kt*64 + nf*16 + (L & 15);
            double s = exact_score(qhi, qlo, khi, klo, base, qq, kk, lane);
            bool kp = ((float)fabs(s)) >= thr;
            if (lane == L) keep[nf][r] = kp;
          }
        }
    }

    #pragma unroll
    for (int nf = 0; nf < 4; nf++)
      #pragma unroll
      for (int r = 0; r < 4; r++){
        u16 ph = f2h(__builtin_amdgcn_exp2f(sa[nf][r] - mh[r]));
        ph = keep[nf][r] ? ph : (u16)0;
        int prow = g*4 + r;
        lP[(w << 10) + (prow << 6) + ((nf*16 + c) ^ ((prow & 7) << 3))] = ph;
      }

    // lP is wave-private (same-wave write->read; compiler orders LDS ops)
    f16x8 pa[2], vb[4][2];
    #pragma unroll
    for (int ks = 0; ks < 2; ks++)
      pa[ks] = *(const f16x8*)&lP[(w << 10) + (c << 6) + ((ks*32 + g*8) ^ ((c & 7) << 3))];
    #pragma unroll
    for (int nf = 0; nf < 4; nf++)
      #pragma unroll
      for (int ks = 0; ks < 2; ks++)
        vb[nf][ks] = *(const f16x8*)&lV[swz(nf*16 + c, ks*32 + g*8)];
    __builtin_amdgcn_s_setprio(1);
    #pragma unroll
    for (int ks = 0; ks < 2; ks++)
      zacc = __builtin_amdgcn_mfma_f32_16x16x32_f16(pa[ks], vones, zacc, 0,0,0);
    #pragma unroll
    for (int nf = 0; nf < 4; nf++)
      #pragma unroll
      for (int ks = 0; ks < 2; ks++)
        O[nf] = __builtin_amdgcn_mfma_f32_16x16x32_f16(pa[ks], vb[nf][ks], O[nf], 0,0,0);
    __builtin_amdgcn_s_setprio(0);
  }

  const int b = bh >> 4, h = bh & 15;
  #pragma unroll
  for (int r = 0; r < 4; r++){
    float z = zacc[r];                     // identical across the 16 c-lanes of this row
    float inv = (z > 0.f) ? (1.0f / z) : 0.f;
    int srow = qrow0 + g*4 + r;
    #pragma unroll
    for (int nf = 0; nf < 4; nf++){
      float v = O[nf][r] * inv;
      int d = nf*16 + c;
      size_t idx = ((size_t)(b*2048 + srow)) * 1024 + h*64 + d;
      ohi[idx] = f2h(v);
    }
  }
}

// ---------------- host ----------------
extern "C" void kernel_launch(void* const* d_in, const int* in_sizes, int n_in,
                              void* d_out, int out_size, void* d_ws, size_t ws_size,
                              hipStream_t stream)
{
  const float* x  = (const float*)d_in[0];
  const float* Wq = (const float*)d_in[1];
  const float* Wk = (const float*)d_in[2];
  const float* Wv = (const float*)d_in[3];
  const float* Wo = (const float*)d_in[4];

  char* p = (char*)d_ws;
  auto alloc = [&](size_t bytes) -> char* {
    char* r = p; p += (bytes + 255) & ~(size_t)255; return r;
  };
  const size_t NX = 4194304, NW = 1048576;
  u16* xh  = (u16*)alloc(NX*2); u16* xl  = (u16*)alloc(NX*2);
  u16* wqh = (u16*)alloc(NW*2); u16* wql = (u16*)alloc(NW*2);
  u16* wkh = (u16*)alloc(NW*2); u16* wkl = (u16*)alloc(NW*2);
  u16* wvh = (u16*)alloc(NW*2);
  u16* woh = (u16*)alloc(NW*2);
  u16* qh  = (u16*)alloc(NX*2); u16* ql  = (u16*)alloc(NX*2);
  u16* kh  = (u16*)alloc(NX*2); u16* kl  = (u16*)alloc(NX*2);
  u16* vth = (u16*)alloc(NX*2);
  u16* oh  = (u16*)alloc(NX*2); u16* ol  = (u16*)alloc(NX*2);
  float*    rowmax = (float*)alloc(65536*4);    // [B*H][S]
  unsigned* histc = (unsigned*)alloc(8192*4);
  unsigned* hist2 = (unsigned*)alloc(8192*4);
  unsigned* ctr   = (unsigned*)alloc(256);
  float*    sc    = (float*)alloc(256);
  float*    bufB  = (float*)alloc(1024*4);
  float*    bufB2 = (float*)alloc(1024*4);
  if ((size_t)(p - (char*)d_ws) > ws_size) return;
  unsigned* candidx = (unsigned*)oh;            // alias: dead before oh written
  float*    candval = (float*)ol;               // alias: ol otherwise unused now

  hipMemsetAsync(histc, 0, 8192*4*2 + 256 + 256, stream);   // histc+hist2+ctr+sc

  dim3 gb(256);
  split_all<<<dim3(2048), gb, 0, stream>>>(x, Wq, Wk, Wv, Wo,
      xh, xl, wqh, wql, wkh, wkl, wvh, woh);

  gemm_projQKV<<<dim3(48, 32), gb, 0, stream>>>(xh, xl, wqh, wql, wkh, wkl, wvh,
                                                qh, ql, kh, kl, vth);

  hist_sub   <<<dim3(256),  gb, 0, stream>>>(qh, kh, histc);
  scan_window<<<dim3(1),    gb, 0, stream>>>(histc, sc);
  collect_k  <<<dim3(1024), gb, 0, stream>>>(qh, kh, sc, candidx, ctr, rowmax);
  refine_k   <<<dim3(2048), gb, 0, stream>>>(qh, ql, kh, kl, candidx, ctr, candval, sc, hist2);
  scan_b     <<<dim3(1),    gb, 0, stream>>>(hist2, ctr);
  extract_k  <<<dim3(64),   gb, 0, stream>>>(candval, ctr, sc, bufB, bufB2);
  final_k    <<<dim3(1),    gb, 0, stream>>>(bufB, bufB2, ctr, sc);
  attn2_k    <<<dim3(1024), gb, 0, stream>>>(qh, ql, kh, kl, vth, rowmax, oh, sc);

  gemm_out<<<dim3(16, 64), gb, 0, stream>>>(oh, woh, (float*)d_out);
}